// Round 10
// baseline (497.300 us; speedup 1.0000x reference)
//
#include <hip/hip_runtime.h>
#include <math.h>

// Problem constants
#define DMODEL 256
#define HEADS  8
#define HDIM   32
#define BS     4
#define NQ     100
#define NPTS   25
#define LQ     2500      // NQ*NPTS
#define M10K   10000     // BS*LQ
#define LEN_IN 21760
#define MVAL   87040     // BS*LEN_IN

typedef float f32x4 __attribute__((ext_vector_type(4)));
typedef short s16x8 __attribute__((ext_vector_type(8)));
typedef unsigned short u16;

// fp32 -> bf16 round-to-nearest-even
static __device__ __forceinline__ short f2bf(float f) {
    unsigned u = __builtin_bit_cast(unsigned, f);
    u = (u + 0x7fffu + ((u >> 16) & 1u)) >> 16;
    return (short)u;
}
static __device__ __forceinline__ unsigned pack2(float lo, float hi) {
    return (unsigned)(u16)f2bf(lo) | ((unsigned)(u16)f2bf(hi) << 16);
}
static __device__ __forceinline__ float bf_lo(unsigned u) {
    return __builtin_bit_cast(float, u << 16);
}
static __device__ __forceinline__ float bf_hi(unsigned u) {
    return __builtin_bit_cast(float, u & 0xffff0000u);
}

#define LDSK   40   // padded bf16 row stride, BK=32 tiles
#define LDSK64 72   // padded bf16 row stride, BK=64 tiles

// ---------------------------------------------------------------------------
// Value GEMM body, fp32 W converted inline (bit-identical rounding to the
// convert_weights path). C[87040,256] = bf16(A fp32) @ bf16(Wf fp32)^T + b.
// BM=64, BN=128, BK=32 (best-known R2 config — do not re-roll).
// ---------------------------------------------------------------------------
static __device__ __forceinline__ void body_value64_wf32(
    char* smem_, const float* __restrict__ A, const float* __restrict__ Wf,
    const float* __restrict__ bias, u16* __restrict__ C, int bx, int by)
{
    short* As = (short*)smem_;            // 64*LDSK = 5120 B
    short* Ws = (short*)(smem_ + 5120);   // 128*LDSK = 10240 B

    const int tid = threadIdx.x;
    const int n0 = bx * 128;
    const int m0 = by * 64;

    const int arow = tid >> 2;
    const int ak = (tid & 3) * 8;
    const int wrow = tid >> 1;
    const int wk = (tid & 1) * 16;

    const float* aptr = A + (size_t)(m0 + arow) * 256 + ak;
    const float* wptr = Wf + (size_t)(n0 + wrow) * 256 + wk;

    const int wave = tid >> 6;
    const int wm = wave & 1, wn = wave >> 1;
    const int lane = tid & 63;
    const int lrow = lane & 15, kq = lane >> 4;

    f32x4 acc[2][4];
#pragma unroll
    for (int i = 0; i < 2; ++i)
#pragma unroll
        for (int j = 0; j < 4; ++j) acc[i][j] = (f32x4)(0.f);

    float4 pa0 = *(const float4*)aptr;
    float4 pa1 = *(const float4*)(aptr + 4);
    float4 pw0 = *(const float4*)(wptr);
    float4 pw1 = *(const float4*)(wptr + 4);
    float4 pw2 = *(const float4*)(wptr + 8);
    float4 pw3 = *(const float4*)(wptr + 12);

    for (int k0 = 0; k0 < 256; k0 += 32) {
        s16x8 av, wv0, wv1;
        av[0]=f2bf(pa0.x); av[1]=f2bf(pa0.y); av[2]=f2bf(pa0.z); av[3]=f2bf(pa0.w);
        av[4]=f2bf(pa1.x); av[5]=f2bf(pa1.y); av[6]=f2bf(pa1.z); av[7]=f2bf(pa1.w);
        wv0[0]=f2bf(pw0.x); wv0[1]=f2bf(pw0.y); wv0[2]=f2bf(pw0.z); wv0[3]=f2bf(pw0.w);
        wv0[4]=f2bf(pw1.x); wv0[5]=f2bf(pw1.y); wv0[6]=f2bf(pw1.z); wv0[7]=f2bf(pw1.w);
        wv1[0]=f2bf(pw2.x); wv1[1]=f2bf(pw2.y); wv1[2]=f2bf(pw2.z); wv1[3]=f2bf(pw2.w);
        wv1[4]=f2bf(pw3.x); wv1[5]=f2bf(pw3.y); wv1[6]=f2bf(pw3.z); wv1[7]=f2bf(pw3.w);
        *(s16x8*)&As[arow * LDSK + ak]     = av;
        *(s16x8*)&Ws[wrow * LDSK + wk]     = wv0;
        *(s16x8*)&Ws[wrow * LDSK + wk + 8] = wv1;
        __syncthreads();
        if (k0 + 32 < 256) {
            pa0 = *(const float4*)(aptr + k0 + 32);
            pa1 = *(const float4*)(aptr + k0 + 36);
            pw0 = *(const float4*)(wptr + k0 + 32);
            pw1 = *(const float4*)(wptr + k0 + 36);
            pw2 = *(const float4*)(wptr + k0 + 40);
            pw3 = *(const float4*)(wptr + k0 + 44);
        }

        s16x8 af[2], bfv[4];
#pragma unroll
        for (int i = 0; i < 2; ++i)
            af[i] = *(const s16x8*)&As[(wm * 32 + i * 16 + lrow) * LDSK + kq * 8];
#pragma unroll
        for (int j = 0; j < 4; ++j)
            bfv[j] = *(const s16x8*)&Ws[(wn * 64 + j * 16 + lrow) * LDSK + kq * 8];
#pragma unroll
        for (int i = 0; i < 2; ++i)
#pragma unroll
            for (int j = 0; j < 4; ++j)
                acc[i][j] = __builtin_amdgcn_mfma_f32_16x16x32_bf16(af[i], bfv[j], acc[i][j], 0, 0, 0);
        __syncthreads();
    }

#pragma unroll
    for (int i = 0; i < 2; ++i)
#pragma unroll
        for (int j = 0; j < 4; ++j) {
            int col = n0 + wn * 64 + j * 16 + lrow;
            float bv = bias[col];
#pragma unroll
            for (int reg = 0; reg < 4; ++reg) {
                int gmo = m0 + wm * 32 + i * 16 + kq * 4 + reg;
                C[(size_t)gmo * 256 + col] = (u16)f2bf(acc[i][j][reg] + bv);
            }
        }
}

// ---------------------------------------------------------------------------
// Fat stage 0: weight conversion (blocks 0..623) + add_convert (624..1873)
// + VALUE GEMM (1874..4593, fp32 W inline-converted).
// ---------------------------------------------------------------------------
__global__ __launch_bounds__(256) void fat_stage0_kernel(
    const float* __restrict__ s0, const float* __restrict__ s1,
    const float* __restrict__ s2, const float* __restrict__ s3,
    const float* __restrict__ s4, const float* __restrict__ s5,
    const float* __restrict__ s6, const float* __restrict__ s7,
    const float* __restrict__ s8, const float* __restrict__ s9,
    u16* __restrict__ dst,
    const float* __restrict__ a, const float* __restrict__ b,
    u16* __restrict__ xb, u16* __restrict__ ab,
    const float* __restrict__ src, const float* __restrict__ valwf,
    const float* __restrict__ valb, u16* __restrict__ valueb)
{
    __shared__ __align__(16) char smem0[15360];
    if (blockIdx.x < 624) {
        int t8 = (blockIdx.x * 256 + threadIdx.x) * 8;
        if (t8 >= 1277952) return;
        const float* s; int base;
        if      (t8 <  196608) { s = s0; base = 0;       }
        else if (t8 <  262144) { s = s1; base = 196608;  }
        else if (t8 <  458752) { s = s2; base = 262144;  }
        else if (t8 <  524288) { s = s3; base = 458752;  }
        else if (t8 <  589824) { s = s4; base = 524288;  }
        else if (t8 <  622592) { s = s5; base = 589824;  }
        else if (t8 <  688128) { s = s6; base = 622592;  }
        else if (t8 <  753664) { s = s7; base = 688128;  }
        else if (t8 < 1015808) { s = s8; base = 753664;  }
        else                   { s = s9; base = 1015808; }
        const float* p = s + (t8 - base);
        float4 fa = *(const float4*)p;
        float4 fb = *(const float4*)(p + 4);
        s16x8 v;
        v[0]=f2bf(fa.x); v[1]=f2bf(fa.y); v[2]=f2bf(fa.z); v[3]=f2bf(fa.w);
        v[4]=f2bf(fb.x); v[5]=f2bf(fb.y); v[6]=f2bf(fb.z); v[7]=f2bf(fb.w);
        *(s16x8*)(dst + t8) = v;
    } else if (blockIdx.x < 1874) {
        int i = (blockIdx.x - 624) * 256 + threadIdx.x;   // < 320000 exactly
        size_t o = (size_t)i * 8;
        float4 a0 = *(const float4*)(a + o);
        float4 a1 = *(const float4*)(a + o + 4);
        s16x8 v;
        v[0]=f2bf(a0.x); v[1]=f2bf(a0.y); v[2]=f2bf(a0.z); v[3]=f2bf(a0.w);
        v[4]=f2bf(a1.x); v[5]=f2bf(a1.y); v[6]=f2bf(a1.z); v[7]=f2bf(a1.w);
        *(s16x8*)(ab + o) = v;
        float4 b0 = *(const float4*)(b + o);
        float4 b1 = *(const float4*)(b + o + 4);
        a0.x += b0.x; a0.y += b0.y; a0.z += b0.z; a0.w += b0.w;
        a1.x += b1.x; a1.y += b1.y; a1.z += b1.z; a1.w += b1.w;
        s16x8 w;
        w[0]=f2bf(a0.x); w[1]=f2bf(a0.y); w[2]=f2bf(a0.z); w[3]=f2bf(a0.w);
        w[4]=f2bf(a1.x); w[5]=f2bf(a1.y); w[6]=f2bf(a1.z); w[7]=f2bf(a1.w);
        *(s16x8*)(xb + o) = w;
    } else {
        const int vb = blockIdx.x - 1874;        // 0..2719 = (2, 1360)
        body_value64_wf32(smem0, src, valwf, valb, valueb, vb & 1, vb >> 1);
    }
}

// ---------------------------------------------------------------------------
// Device bodies for fat stage 1 (shared 20480-B LDS buffer).
// ---------------------------------------------------------------------------

// 128x128-tile GEMM body: K=256, lda=256, ldc=768, bf16 out, M=10000 bound.
// (intra QK projection)
static __device__ __forceinline__ void body_mfma128(
    char* smem_, const u16* __restrict__ A, const u16* __restrict__ W,
    const float* __restrict__ bias, u16* __restrict__ Cv, int bx, int by)
{
    short* As = (short*)smem_;             // 10240 B
    short* Ws = (short*)(smem_ + 10240);   // 10240 B

    const int tid = threadIdx.x;
    const int m0 = by * 128, n0 = bx * 128;
    const int srow = tid >> 1;
    const int sk = (tid & 1) * 16;
    const int wave = tid >> 6;
    const int wm = wave & 1, wn = wave >> 1;
    const int lane = tid & 63;
    const int lrow = lane & 15, kq = lane >> 4;

    const int gm = m0 + srow;
    const u16* aptr = A + (size_t)gm * 256 + sk;
    const u16* wptr = W + (size_t)(n0 + srow) * 256 + sk;

    f32x4 acc[4][4];
#pragma unroll
    for (int i = 0; i < 4; ++i)
#pragma unroll
        for (int j = 0; j < 4; ++j) acc[i][j] = (f32x4)(0.f);

    s16x8 a0 = (s16x8)0, a1 = (s16x8)0, w0, w1;
    if (gm < M10K) { a0 = *(const s16x8*)aptr; a1 = *(const s16x8*)(aptr + 8); }
    w0 = *(const s16x8*)wptr; w1 = *(const s16x8*)(wptr + 8);

    for (int k0 = 0; k0 < 256; k0 += 32) {
        *(s16x8*)&As[srow * LDSK + sk]     = a0;
        *(s16x8*)&As[srow * LDSK + sk + 8] = a1;
        *(s16x8*)&Ws[srow * LDSK + sk]     = w0;
        *(s16x8*)&Ws[srow * LDSK + sk + 8] = w1;
        __syncthreads();
        if (k0 + 32 < 256) {
            if (gm < M10K) {
                a0 = *(const s16x8*)(aptr + k0 + 32);
                a1 = *(const s16x8*)(aptr + k0 + 40);
            }
            w0 = *(const s16x8*)(wptr + k0 + 32);
            w1 = *(const s16x8*)(wptr + k0 + 40);
        }

        s16x8 af[4], bfv[4];
#pragma unroll
        for (int i = 0; i < 4; ++i)
            af[i] = *(const s16x8*)&As[(wm * 64 + i * 16 + lrow) * LDSK + kq * 8];
#pragma unroll
        for (int j = 0; j < 4; ++j)
            bfv[j] = *(const s16x8*)&Ws[(wn * 64 + j * 16 + lrow) * LDSK + kq * 8];
#pragma unroll
        for (int i = 0; i < 4; ++i)
#pragma unroll
            for (int j = 0; j < 4; ++j)
                acc[i][j] = __builtin_amdgcn_mfma_f32_16x16x32_bf16(af[i], bfv[j], acc[i][j], 0, 0, 0);
        __syncthreads();
    }

#pragma unroll
    for (int i = 0; i < 4; ++i)
#pragma unroll
        for (int j = 0; j < 4; ++j) {
            int col = n0 + wn * 64 + j * 16 + lrow;
            float bv = bias[col];
#pragma unroll
            for (int reg = 0; reg < 4; ++reg) {
                int gmo = m0 + wm * 64 + i * 16 + kq * 4 + reg;
                if (gmo < M10K)
                    Cv[(size_t)gmo * 768 + col] = (u16)f2bf(acc[i][j][reg] + bv);
            }
        }
}

// 64x64-tile GEMM body, BK=64: K=256, lda=256, ldc=768, bf16 out, M=10000.
// (intra V projection)
static __device__ __forceinline__ void body_mfma64(
    char* smem_, const u16* __restrict__ A, const u16* __restrict__ W,
    const float* __restrict__ bias, u16* __restrict__ Cv, int bx, int by)
{
    short* As = (short*)smem_;            // 64*LDSK64*2 = 9216 B
    short* Ws = (short*)(smem_ + 9216);   // 9216 B

    const int tid = threadIdx.x;
    const int m0 = by * 64, n0 = bx * 64;
    const int srow = tid >> 2;
    const int sk = (tid & 3) * 16;
    const int wave = tid >> 6;
    const int wm = wave & 1, wn = wave >> 1;
    const int lane = tid & 63;
    const int lrow = lane & 15, kq = lane >> 4;

    const int gm = m0 + srow;
    const u16* aptr = A + (size_t)gm * 256 + sk;
    const u16* wptr = W + (size_t)(n0 + srow) * 256 + sk;

    f32x4 acc[2][2];
#pragma unroll
    for (int i = 0; i < 2; ++i)
#pragma unroll
        for (int j = 0; j < 2; ++j) acc[i][j] = (f32x4)(0.f);

    s16x8 a0 = (s16x8)0, a1 = (s16x8)0, w0, w1;
    if (gm < M10K) { a0 = *(const s16x8*)aptr; a1 = *(const s16x8*)(aptr + 8); }
    w0 = *(const s16x8*)wptr; w1 = *(const s16x8*)(wptr + 8);

    for (int k0 = 0; k0 < 256; k0 += 64) {
        *(s16x8*)&As[srow * LDSK64 + sk]     = a0;
        *(s16x8*)&As[srow * LDSK64 + sk + 8] = a1;
        *(s16x8*)&Ws[srow * LDSK64 + sk]     = w0;
        *(s16x8*)&Ws[srow * LDSK64 + sk + 8] = w1;
        __syncthreads();
        if (k0 + 64 < 256) {
            if (gm < M10K) {
                a0 = *(const s16x8*)(aptr + k0 + 64);
                a1 = *(const s16x8*)(aptr + k0 + 72);
            }
            w0 = *(const s16x8*)(wptr + k0 + 64);
            w1 = *(const s16x8*)(wptr + k0 + 72);
        }

#pragma unroll
        for (int s = 0; s < 2; ++s) {
            s16x8 af[2], bfv[2];
#pragma unroll
            for (int i = 0; i < 2; ++i)
                af[i] = *(const s16x8*)&As[(wm * 32 + i * 16 + lrow) * LDSK64 + s * 32 + kq * 8];
#pragma unroll
            for (int j = 0; j < 2; ++j)
                bfv[j] = *(const s16x8*)&Ws[(wn * 32 + j * 16 + lrow) * LDSK64 + s * 32 + kq * 8];
#pragma unroll
            for (int i = 0; i < 2; ++i)
#pragma unroll
                for (int j = 0; j < 2; ++j)
                    acc[i][j] = __builtin_amdgcn_mfma_f32_16x16x32_bf16(af[i], bfv[j], acc[i][j], 0, 0, 0);
        }
        __syncthreads();
    }

#pragma unroll
    for (int i = 0; i < 2; ++i)
#pragma unroll
        for (int j = 0; j < 2; ++j) {
            int col = n0 + wn * 32 + j * 16 + lrow;
            float bv = bias[col];
#pragma unroll
            for (int reg = 0; reg < 4; ++reg) {
                int gmo = m0 + wm * 32 + i * 16 + kq * 4 + reg;
                if (gmo < M10K)
                    Cv[(size_t)gmo * 768 + col] = (u16)f2bf(acc[i][j][reg] + bv);
            }
        }
}

// ---------------------------------------------------------------------------
// Fat stage 1: intra-QK GEMM (blocks 0..315) + intra-V GEMM (316..943).
// ---------------------------------------------------------------------------
__global__ __launch_bounds__(256) void fat_stage1_kernel(
    const u16* __restrict__ x1b, const u16* __restrict__ wqk,
    const float* __restrict__ bqk, u16* __restrict__ qkvb,
    const u16* __restrict__ tgtb, const u16* __restrict__ wv,
    const float* __restrict__ bv, u16* __restrict__ qkvb_v)
{
    __shared__ __align__(16) char smem[20480];
    const int b = blockIdx.x;
    if (b < 316) {                               // 316 = (4, 79)
        body_mfma128(smem, x1b, wqk, bqk, qkvb, b & 3, b >> 2);
    } else {
        const int bb = b - 316;                  // 628 = (4, 157)
        body_mfma64(smem, tgtb, wv, bv, qkvb_v, bb & 3, bb >> 2);
    }
}

// ---------------------------------------------------------------------------
// Fused GEMM + residual + LayerNorm, BM=64 x BN=256 (full row per block).
// x = res[r] + A[r]@W^T + bias;  y = LN(x)*g + beta over 256 cols.
// Each wave owns 16 COMPLETE rows -> LN needs no cross-wave reduce (in-thread
// sum over 16 col-fragments + 4 shfl_xor within the 16-lane quad group).
// W traffic per block (256xK slice, streamed BK=32 from L2) == the 4-way
// n-split version's aggregate — unlike R5's BM=16 failure (16x worse econ).
// Replaces GEMM + add_ln pairs: -1 dispatch, -tmp round-trip each.
// tmode: 0 none; 1 ti-row -> tgt-row; 2 tgt-row -> ti-row.
// Optional outbf mirror and qout = bf16(y + qp[ro]).
// Grid: 157 ((M10K+63)/64). LDS 25.6 KB.
// ---------------------------------------------------------------------------
__global__ __launch_bounds__(256) void gemm_ln64_kernel(
    const u16* __restrict__ A, int lda,
    const u16* __restrict__ W, int K,
    const float* __restrict__ bias,
    const float* __restrict__ res,
    const float* __restrict__ g, const float* __restrict__ beta,
    float* __restrict__ outf, u16* __restrict__ outbf,
    const float* __restrict__ qp, u16* __restrict__ qout,
    int tmode)
{
    __shared__ short As[64 * LDSK];    // 5.1 KB
    __shared__ short Ws[256 * LDSK];   // 20.5 KB

    const int tid = threadIdx.x;
    const int m0 = blockIdx.x * 64;
    const int wave = tid >> 6, lane = tid & 63;
    const int lrow = lane & 15, kq = lane >> 4;

    const int arow = tid >> 2, ak = (tid & 3) * 8;
    const int gm = m0 + arow;
    const u16* aptr = A + (size_t)gm * lda + ak;
    const u16* wptr = W + (size_t)tid * K;

    f32x4 acc[16];
#pragma unroll
    for (int j = 0; j < 16; ++j) acc[j] = (f32x4)(0.f);

    s16x8 a0 = (s16x8)0, w0, w1, w2, w3;
    if (gm < M10K) a0 = *(const s16x8*)aptr;
    w0 = *(const s16x8*)(wptr);
    w1 = *(const s16x8*)(wptr + 8);
    w2 = *(const s16x8*)(wptr + 16);
    w3 = *(const s16x8*)(wptr + 24);

    for (int k0 = 0; k0 < K; k0 += 32) {
        *(s16x8*)&As[arow * LDSK + ak] = a0;
        *(s16x8*)&Ws[tid * LDSK +  0] = w0;
        *(s16x8*)&Ws[tid * LDSK +  8] = w1;
        *(s16x8*)&Ws[tid * LDSK + 16] = w2;
        *(s16x8*)&Ws[tid * LDSK + 24] = w3;
        __syncthreads();
        if (k0 + 32 < K) {
            if (gm < M10K) a0 = *(const s16x8*)(aptr + k0 + 32);
            w0 = *(const s16x8*)(wptr + k0 + 32);
            w1 = *(const s16x8*)(wptr + k0 + 40);
            w2 = *(const s16x8*)(wptr + k0 + 48);
            w3 = *(const s16x8*)(wptr + k0 + 56);
        }

        s16x8 af = *(const s16x8*)&As[(wave * 16 + lrow) * LDSK + kq * 8];
#pragma unroll
        for (int j = 0; j < 16; ++j) {
            s16x8 bfv = *(const s16x8*)&Ws[(j * 16 + lrow) * LDSK + kq * 8];
            acc[j] = __builtin_amdgcn_mfma_f32_16x16x32_bf16(af, bfv, acc[j], 0, 0, 0);
        }
        __syncthreads();
    }

    // ---- epilogue: x = res + acc + bias; per-row LN (wave-local) ----
    const int rbase = m0 + wave * 16 + kq * 4;
    float x[4][16];
#pragma unroll
    for (int reg = 0; reg < 4; ++reg) {
        const int r = rbase + reg;
        const bool ok = (r < M10K);
#pragma unroll
        for (int j = 0; j < 16; ++j) {
            const int col = j * 16 + lrow;
            const float rv = ok ? res[(size_t)r * 256 + col] : 0.f;
            x[reg][j] = rv + acc[j][reg] + bias[col];
        }
    }

    float mean[4], rstd[4];
#pragma unroll
    for (int reg = 0; reg < 4; ++reg) {
        float s = 0.f;
#pragma unroll
        for (int j = 0; j < 16; ++j) s += x[reg][j];
        s += __shfl_xor(s, 1); s += __shfl_xor(s, 2);
        s += __shfl_xor(s, 4); s += __shfl_xor(s, 8);
        mean[reg] = s * (1.f / 256.f);
        float vs = 0.f;
#pragma unroll
        for (int j = 0; j < 16; ++j) {
            const float d = x[reg][j] - mean[reg];
            vs += d * d;
        }
        vs += __shfl_xor(vs, 1); vs += __shfl_xor(vs, 2);
        vs += __shfl_xor(vs, 4); vs += __shfl_xor(vs, 8);
        rstd[reg] = rsqrtf(vs * (1.f / 256.f) + 1e-5f);
    }

#pragma unroll
    for (int reg = 0; reg < 4; ++reg) {
        const int r = rbase + reg;
        if (r >= M10K) continue;
        size_t ro = r;
        if (tmode == 1) {
            int q = r % 100; int bp = r / 100; int p = bp % 25; int bb = bp / 25;
            ro = ((size_t)bb * 100 + q) * 25 + p;
        } else if (tmode == 2) {
            int p = r % 25; int t = r / 25; int q = t % 100; int bb = t / 100;
            ro = ((size_t)bb * 25 + p) * 100 + q;
        }
#pragma unroll
        for (int j = 0; j < 16; ++j) {
            const int col = j * 16 + lrow;
            const float y = (x[reg][j] - mean[reg]) * rstd[reg] * g[col] + beta[col];
            outf[ro * 256 + col] = y;
            if (outbf) outbf[ro * 256 + col] = (u16)f2bf(y);
            if (qout)  qout[ro * 256 + col] = (u16)f2bf(y + qp[ro * 256 + col]);
        }
    }
}

// ---------------------------------------------------------------------------
// 64x64-tile bf16 MFMA GEMM, BK=64, register prefetch (standalone).
// C[M,N] = A[M,K] @ W[N,K]^T + bias[N]. K % 64 == 0.
// Dual-output: cols >= ncut go to Cv2 (fp32, ldc2) with bias2.
// (remaining use: off/aw dual GEMM)
// ---------------------------------------------------------------------------
__global__ __launch_bounds__(256) void gemm_mfma_kernel(
    const u16* __restrict__ A, int lda,
    const u16* __restrict__ W, int K,
    const float* __restrict__ bias,
    void* __restrict__ Cv, int ldc,
    int M, int relu, int out_bf16,
    int ncut, const float* __restrict__ bias2,
    float* __restrict__ Cv2, int ldc2)
{
    __shared__ short As[64 * LDSK64];   // 9.2 KB
    __shared__ short Ws[64 * LDSK64];   // 9.2 KB

    const int tid = threadIdx.x;
    const int m0 = blockIdx.y * 64, n0 = blockIdx.x * 64;
    const int srow = tid >> 2;
    const int sk = (tid & 3) * 16;      // 0,16,32,48
    const int wave = tid >> 6;
    const int wm = wave & 1, wn = wave >> 1;
    const int lane = tid & 63;
    const int lrow = lane & 15;
    const int kq = lane >> 4;

    const int gm = m0 + srow;
    const u16* aptr = A + (size_t)gm * lda + sk;
    const u16* wptr = W + (size_t)(n0 + srow) * K + sk;

    f32x4 acc[2][2];
#pragma unroll
    for (int i = 0; i < 2; ++i)
#pragma unroll
        for (int j = 0; j < 2; ++j) acc[i][j] = (f32x4)(0.f);

    s16x8 a0 = (s16x8)0, a1 = (s16x8)0, w0, w1;
    if (gm < M) { a0 = *(const s16x8*)aptr; a1 = *(const s16x8*)(aptr + 8); }
    w0 = *(const s16x8*)wptr; w1 = *(const s16x8*)(wptr + 8);

    for (int k0 = 0; k0 < K; k0 += 64) {
        *(s16x8*)&As[srow * LDSK64 + sk]     = a0;
        *(s16x8*)&As[srow * LDSK64 + sk + 8] = a1;
        *(s16x8*)&Ws[srow * LDSK64 + sk]     = w0;
        *(s16x8*)&Ws[srow * LDSK64 + sk + 8] = w1;
        __syncthreads();
        if (k0 + 64 < K) {
            if (gm < M) {
                a0 = *(const s16x8*)(aptr + k0 + 64);
                a1 = *(const s16x8*)(aptr + k0 + 72);
            }
            w0 = *(const s16x8*)(wptr + k0 + 64);
            w1 = *(const s16x8*)(wptr + k0 + 72);
        }

#pragma unroll
        for (int s = 0; s < 2; ++s) {
            s16x8 af[2], bfv[2];
#pragma unroll
            for (int i = 0; i < 2; ++i)
                af[i] = *(const s16x8*)&As[(wm * 32 + i * 16 + lrow) * LDSK64 + s * 32 + kq * 8];
#pragma unroll
            for (int j = 0; j < 2; ++j)
                bfv[j] = *(const s16x8*)&Ws[(wn * 32 + j * 16 + lrow) * LDSK64 + s * 32 + kq * 8];
#pragma unroll
            for (int i = 0; i < 2; ++i)
#pragma unroll
                for (int j = 0; j < 2; ++j)
                    acc[i][j] = __builtin_amdgcn_mfma_f32_16x16x32_bf16(af[i], bfv[j], acc[i][j], 0, 0, 0);
        }
        __syncthreads();
    }

#pragma unroll
    for (int i = 0; i < 2; ++i)
#pragma unroll
        for (int j = 0; j < 2; ++j) {
            int col = n0 + wn * 32 + j * 16 + lrow;
            float bv = (col < ncut) ? bias[col] : bias2[col - ncut];
#pragma unroll
            for (int reg = 0; reg < 4; ++reg) {
                int gmo = m0 + wm * 32 + i * 16 + kq * 4 + reg;
                if (gmo < M) {
                    float v = acc[i][j][reg] + bv;
                    if (relu) v = fmaxf(v, 0.f);
                    if (col < ncut) {
                        if (out_bf16)
                            ((u16*)Cv)[(size_t)gmo * ldc + col] = (u16)f2bf(v);
                        else
                            ((float*)Cv)[(size_t)gmo * ldc + col] = v;
                    } else {
                        Cv2[(size_t)gmo * ldc2 + (col - ncut)] = v;
                    }
                }
            }
        }
}

// ---------------------------------------------------------------------------
// 128x128-tile bf16 MFMA GEMM, BK=64. K % 64 == 0. (inter QKV, FFN1)
// ---------------------------------------------------------------------------
__global__ __launch_bounds__(256) void gemm_mfma128_kernel(
    const u16* __restrict__ A, int lda,
    const u16* __restrict__ W, int K,
    const float* __restrict__ bias,
    void* __restrict__ Cv, int ldc,
    int M, int relu, int out_bf16)
{
    __shared__ short As[128 * LDSK64];   // 18.4 KB
    __shared__ short Ws[128 * LDSK64];   // 18.4 KB

    const int tid = threadIdx.x;
    const int m0 = blockIdx.y * 128, n0 = blockIdx.x * 128;

    const int srow = tid >> 1;            // 0..127
    const int sk = (tid & 1) * 32;        // 0 or 32

    const int wave = tid >> 6;
    const int wm = wave & 1, wn = wave >> 1;
    const int lane = tid & 63;
    const int lrow = lane & 15;
    const int kq = lane >> 4;

    const int gm = m0 + srow;
    const u16* aptr = A + (size_t)gm * lda + sk;
    const u16* wptr = W + (size_t)(n0 + srow) * K + sk;

    f32x4 acc[4][4];
#pragma unroll
    for (int i = 0; i < 4; ++i)
#pragma unroll
        for (int j = 0; j < 4; ++j) acc[i][j] = (f32x4)(0.f);

    s16x8 a0 = (s16x8)0, a1 = (s16x8)0, a2 = (s16x8)0, a3 = (s16x8)0;
    s16x8 w0, w1, w2, w3;
    if (gm < M) {
        a0 = *(const s16x8*)aptr;        a1 = *(const s16x8*)(aptr + 8);
        a2 = *(const s16x8*)(aptr + 16); a3 = *(const s16x8*)(aptr + 24);
    }
    w0 = *(const s16x8*)wptr;        w1 = *(const s16x8*)(wptr + 8);
    w2 = *(const s16x8*)(wptr + 16); w3 = *(const s16x8*)(wptr + 24);

    for (int k0 = 0; k0 < K; k0 += 64) {
        *(s16x8*)&As[srow * LDSK64 + sk]      = a0;
        *(s16x8*)&As[srow * LDSK64 + sk + 8]  = a1;
        *(s16x8*)&As[srow * LDSK64 + sk + 16] = a2;
        *(s16x8*)&As[srow * LDSK64 + sk + 24] = a3;
        *(s16x8*)&Ws[srow * LDSK64 + sk]      = w0;
        *(s16x8*)&Ws[srow * LDSK64 + sk + 8]  = w1;
        *(s16x8*)&Ws[srow * LDSK64 + sk + 16] = w2;
        *(s16x8*)&Ws[srow * LDSK64 + sk + 24] = w3;
        __syncthreads();
        if (k0 + 64 < K) {
            if (gm < M) {
                a0 = *(const s16x8*)(aptr + k0 + 64);
                a1 = *(const s16x8*)(aptr + k0 + 72);
                a2 = *(const s16x8*)(aptr + k0 + 80);
                a3 = *(const s16x8*)(aptr + k0 + 88);
            }
            w0 = *(const s16x8*)(wptr + k0 + 64);
            w1 = *(const s16x8*)(wptr + k0 + 72);
            w2 = *(const s16x8*)(wptr + k0 + 80);
            w3 = *(const s16x8*)(wptr + k0 + 88);
        }

#pragma unroll
        for (int s = 0; s < 2; ++s) {
            s16x8 af[4], bfv[4];
#pragma unroll
            for (int i = 0; i < 4; ++i)
                af[i] = *(const s16x8*)&As[(wm * 64 + i * 16 + lrow) * LDSK64 + s * 32 + kq * 8];
#pragma unroll
            for (int j = 0; j < 4; ++j)
                bfv[j] = *(const s16x8*)&Ws[(wn * 64 + j * 16 + lrow) * LDSK64 + s * 32 + kq * 8];
#pragma unroll
            for (int i = 0; i < 4; ++i)
#pragma unroll
                for (int j = 0; j < 4; ++j)
                    acc[i][j] = __builtin_amdgcn_mfma_f32_16x16x32_bf16(af[i], bfv[j], acc[i][j], 0, 0, 0);
        }
        __syncthreads();
    }

#pragma unroll
    for (int i = 0; i < 4; ++i)
#pragma unroll
        for (int j = 0; j < 4; ++j) {
            int col = n0 + wn * 64 + j * 16 + lrow;
            float bv = bias[col];
#pragma unroll
            for (int reg = 0; reg < 4; ++reg) {
                int gmo = m0 + wm * 64 + i * 16 + kq * 4 + reg;
                if (gmo < M) {
                    float v = acc[i][j][reg] + bv;
                    if (relu) v = fmaxf(v, 0.f);
                    if (out_bf16)
                        ((u16*)Cv)[(size_t)gmo * ldc + col] = (u16)f2bf(v);
                    else
                        ((float*)Cv)[(size_t)gmo * ldc + col] = v;
                }
            }
        }
}

// ---------------------------------------------------------------------------
// Inter attention (S=100) via MFMA flash, bf16 qkv input.
// One block (256 thr) per (b,h).
// ---------------------------------------------------------------------------
__global__ __launch_bounds__(256) void inter_attn_mfma_kernel(
    const u16* __restrict__ qkv, u16* __restrict__ out, float scale)
{
    __shared__ __align__(16) u16 Qs[112 * 40];
    __shared__ __align__(16) u16 Ks[112 * 40];
    __shared__ __align__(16) u16 Vt[32 * 136];
    __shared__ __align__(16) u16 Ps[112 * 136];

    const int b = blockIdx.x, h = blockIdx.y;
    const u16* base = qkv + (size_t)b * 100 * 768;
    const int tid = threadIdx.x;
    const int wave = tid >> 6, lane = tid & 63;
    const int lr = lane & 15, quad = lane >> 4;

    for (int i = tid; i < 12 * 20; i += 256) {
        int row = 100 + i / 20, c = (i % 20) * 2;
        *(unsigned*)&Qs[row * 40 + c] = 0;
        *(unsigned*)&Ks[row * 40 + c] = 0;
    }
    for (int i = tid; i < 2176; i += 256) ((unsigned*)Vt)[i] = 0;
    for (int i = tid; i < 7616; i += 256) ((unsigned*)Ps)[i] = 0;
    __syncthreads();

    for (int idx = tid; idx < 2400; idx += 256) {
        int row = idx / 24, s = idx % 24;
        const u16* p = (s < 8)  ? base + row * 768 + h * 32 + s * 4
                     : (s < 16) ? base + row * 768 + 256 + h * 32 + (s - 8) * 4
                                : base + row * 768 + 512 + h * 32 + (s - 16) * 4;
        if (s < 8) {
            *(uint2*)&Qs[row * 40 + s * 4] = *(const uint2*)p;
        } else if (s < 16) {
            *(uint2*)&Ks[row * 40 + (s - 8) * 4] = *(const uint2*)p;
        } else {
            int d0 = (s - 16) * 4;
            Vt[(d0 + 0) * 136 + row] = p[0];
            Vt[(d0 + 1) * 136 + row] = p[1];
            Vt[(d0 + 2) * 136 + row] = p[2];
            Vt[(d0 + 3) * 136 + row] = p[3];
        }
    }
    __syncthreads();

#pragma unroll 1
    for (int rr = 0; rr < 2; ++rr) {
        int rt = wave + rr * 4;
        if (rt < 7) {
            s16x8 aq = *(const s16x8*)&Qs[(rt * 16 + lr) * 40 + quad * 8];
            f32x4 sc[7];
#pragma unroll
            for (int ct = 0; ct < 7; ++ct) {
                s16x8 bk = *(const s16x8*)&Ks[(ct * 16 + lr) * 40 + quad * 8];
                sc[ct] = __builtin_amdgcn_mfma_f32_16x16x32_bf16(aq, bk, (f32x4)(0.f), 0, 0, 0);
            }
            const bool colok[7] = {true, true, true, true, true, true, (lr < 4)};
#pragma unroll
            for (int reg = 0; reg < 4; ++reg) {
                float mx = -1e30f;
#pragma unroll
                for (int ct = 0; ct < 7; ++ct) {
                    float sv = sc[ct][reg] * scale;
                    sc[ct][reg] = sv;
                    if (colok[ct]) mx = fmaxf(mx, sv);
                }
#pragma unroll
                for (int d = 1; d < 16; d <<= 1) mx = fmaxf(mx, __shfl_xor(mx, d));
                float ssum = 0.f;
#pragma unroll
                for (int ct = 0; ct < 7; ++ct) {
                    float pv = colok[ct] ? __expf(sc[ct][reg] - mx) : 0.f;
                    sc[ct][reg] = pv;
                    ssum += pv;
                }
#pragma unroll
                for (int d = 1; d < 16; d <<= 1) ssum += __shfl_xor(ssum, d);
                float inv = 1.f / ssum;
                int prow = rt * 16 + quad * 4 + reg;
#pragma unroll
                for (int ct = 0; ct < 7; ++ct)
                    Ps[prow * 136 + ct * 16 + lr] = (u16)f2bf(sc[ct][reg] * inv);
            }
        }
    }
    __syncthreads();

#pragma unroll 1
    for (int rr = 0; rr < 2; ++rr) {
        int rt = wave + rr * 4;
        if (rt < 7) {
            f32x4 o0 = (f32x4)(0.f), o1 = (f32x4)(0.f);
#pragma unroll
            for (int kk = 0; kk < 4; ++kk) {
                s16x8 ap = *(const s16x8*)&Ps[(rt * 16 + lr) * 136 + kk * 32 + quad * 8];
                s16x8 bv0 = *(const s16x8*)&Vt[lr * 136 + kk * 32 + quad * 8];
                s16x8 bv1 = *(const s16x8*)&Vt[(16 + lr) * 136 + kk * 32 + quad * 8];
                o0 = __builtin_amdgcn_mfma_f32_16x16x32_bf16(ap, bv0, o0, 0, 0, 0);
                o1 = __builtin_amdgcn_mfma_f32_16x16x32_bf16(ap, bv1, o1, 0, 0, 0);
            }
#pragma unroll
            for (int reg = 0; reg < 4; ++reg) {
                int q = rt * 16 + quad * 4 + reg;
                if (q < 100) {
                    u16* op = out + ((size_t)b * 100 + q) * 256 + h * 32;
                    op[lr]      = (u16)f2bf(o0[reg]);
                    op[16 + lr] = (u16)f2bf(o1[reg]);
                }
            }
        }
    }
}

// ---------------------------------------------------------------------------
// FUSED intra path: flash attn (S=25, bf16 qkv) + out-projection (W from L2)
// + residual + LayerNorm + transpose-to-ti write. One block per instance.
// ---------------------------------------------------------------------------
__global__ __launch_bounds__(256) void intra_fused_kernel(
    const u16* __restrict__ qkv,        // [400*25][768] bf16
    const u16* __restrict__ W,          // out-proj [256][256] bf16
    const float* __restrict__ bias,
    const float* __restrict__ res,      // tgt fp32 [10000][256]
    const float* __restrict__ g, const float* __restrict__ beta,
    float* __restrict__ outf, u16* __restrict__ outbf,  // ti / tib (mode-2)
    float scale)
{
    __shared__ __align__(16) uint2 KVh[25][128];   // 25.6 KB (K|V bf16)
    __shared__ __align__(16) u16 Ao[32 * 264];     // 16.9 KB attn out (pad rows 0)
    __shared__ short Ws[256 * LDSK];               // 20.5 KB W K-slice
    __shared__ float redS[4][32];
    __shared__ float redV[4][32];

    const int inst = blockIdx.x;                   // 0..399 = bb*100 + qq
    const int tid = threadIdx.x;
    const int h = tid >> 5, r = tid & 31;
    const u16* base = qkv + (size_t)inst * 25 * 768;

    // zero Ao pad rows 25..31 (cols read by MFMA must be 0)
    for (int i = tid; i < 7 * 132; i += 256)
        ((unsigned*)&Ao[25 * 264])[i] = 0;
    // stage K,V bf16
    for (int idx = tid; idx < 3200; idx += 256) {
        int row = idx >> 7, c = idx & 127;
        KVh[row][c] = *(const uint2*)(base + row * 768 + 256 + c * 4);
    }

    float q[32];
    if (r < 25) {
        const u16* qp = base + r * 768 + h * 32;
#pragma unroll
        for (int c4 = 0; c4 < 8; ++c4) {
            uint2 u = *(const uint2*)(qp + c4 * 4);
            q[c4*4+0] = bf_lo(u.x); q[c4*4+1] = bf_hi(u.x);
            q[c4*4+2] = bf_lo(u.y); q[c4*4+3] = bf_hi(u.y);
        }
    }
    __syncthreads();

    if (r < 25) {
        float m = -1e30f, l = 0.f, acc[32];
#pragma unroll
        for (int c = 0; c < 32; ++c) acc[c] = 0.f;
#pragma unroll 2
        for (int j = 0; j < 25; ++j) {
            const uint2* kr = &KVh[j][h * 8];
            float dot = 0.f;
#pragma unroll
            for (int c4 = 0; c4 < 8; ++c4) {
                uint2 u = kr[c4];
                dot = fmaf(q[c4*4+0], bf_lo(u.x), dot);
                dot = fmaf(q[c4*4+1], bf_hi(u.x), dot);
                dot = fmaf(q[c4*4+2], bf_lo(u.y), dot);
                dot = fmaf(q[c4*4+3], bf_hi(u.y), dot);
            }
            dot *= scale;
            float mn = fmaxf(m, dot);
            float alpha = __expf(m - mn);
            float p = __expf(dot - mn);
            l = l * alpha + p;
            const uint2* vr = &KVh[j][64 + h * 8];
#pragma unroll
            for (int c4 = 0; c4 < 8; ++c4) {
                uint2 u = vr[c4];
                acc[c4*4+0] = acc[c4*4+0] * alpha + p * bf_lo(u.x);
                acc[c4*4+1] = acc[c4*4+1] * alpha + p * bf_hi(u.x);
                acc[c4*4+2] = acc[c4*4+2] * alpha + p * bf_lo(u.y);
                acc[c4*4+3] = acc[c4*4+3] * alpha + p * bf_hi(u.y);
            }
            m = mn;
        }
        float inv = 1.f / l;
        unsigned* op = (unsigned*)&Ao[r * 264 + h * 32];
#pragma unroll
        for (int c = 0; c < 16; ++c)
            op[c] = pack2(acc[2*c] * inv, acc[2*c+1] * inv);
    }

    // ---- projection: [25(32) x 256] @ W^T, K=256, BK=32 ----
    const int wave = tid >> 6, lane = tid & 63;
    const int lrow = lane & 15, kq = lane >> 4;

    f32x4 acc2[2][4];
#pragma unroll
    for (int i = 0; i < 2; ++i)
#pragma unroll
        for (int j = 0; j < 4; ++j) acc2[i][j] = (f32x4)(0.f);

    const u16* wptr = W + (size_t)tid * 256;   // thread -> W row (out col)
    for (int k0 = 0; k0 < 256; k0 += 32) {
        __syncthreads();   // Ws free to overwrite (and Ao ready on 1st iter)
        *(s16x8*)&Ws[tid * LDSK +  0] = *(const s16x8*)(wptr + k0);
        *(s16x8*)&Ws[tid * LDSK +  8] = *(const s16x8*)(wptr + k0 + 8);
        *(s16x8*)&Ws[tid * LDSK + 16] = *(const s16x8*)(wptr + k0 + 16);
        *(s16x8*)&Ws[tid * LDSK + 24] = *(const s16x8*)(wptr + k0 + 24);
        __syncthreads();

        s16x8 af[2], bfv[4];
#pragma unroll
        for (int i = 0; i < 2; ++i)
            af[i] = *(const s16x8*)&Ao[(i * 16 + lrow) * 264 + k0 + kq * 8];
#pragma unroll
        for (int j = 0; j < 4; ++j)
            bfv[j] = *(const s16x8*)&Ws[(wave * 64 + j * 16 + lrow) * LDSK + kq * 8];
#pragma unroll
        for (int i = 0; i < 2; ++i)
#pragma unroll
            for (int j = 0; j < 4; ++j)
                acc2[i][j] = __builtin_amdgcn_mfma_f32_16x16x32_bf16(af[i], bfv[j], acc2[i][j], 0, 0, 0);
    }

    // ---- epilogue: x = res + proj + bias; two-pass LN; transposed write ----
    const int qq = inst % 100, bb = inst / 100;
    float x[2][4][4];
#pragma unroll
    for (int i = 0; i < 2; ++i)
#pragma unroll
        for (int j = 0; j < 4; ++j) {
            const int col = wave * 64 + j * 16 + lrow;
            const float bv = bias[col];
#pragma unroll
            for (int reg = 0; reg < 4; ++reg) {
                const int rowp = i * 16 + kq * 4 + reg;
                float rv = (rowp < 25) ? res[((size_t)inst * 25 + rowp) * 256 + col] : 0.f;
                x[i][j][reg] = rv + (acc2[i][j][reg] + bv);
            }
        }

#pragma unroll
    for (int i = 0; i < 2; ++i)
#pragma unroll
        for (int reg = 0; reg < 4; ++reg) {
            float s = x[i][0][reg] + x[i][1][reg] + x[i][2][reg] + x[i][3][reg];
            s += __shfl_xor(s, 1); s += __shfl_xor(s, 2);
            s += __shfl_xor(s, 4); s += __shfl_xor(s, 8);
            if (lrow == 0) redS[wave][i * 16 + kq * 4 + reg] = s;
        }
    __syncthreads();
    float mean[2][4];
#pragma unroll
    for (int i = 0; i < 2; ++i)
#pragma unroll
        for (int reg = 0; reg < 4; ++reg) {
            const int rowp = i * 16 + kq * 4 + reg;
            mean[i][reg] = (redS[0][rowp] + redS[1][rowp] + redS[2][rowp] + redS[3][rowp]) * (1.f / 256.f);
        }
#pragma unroll
    for (int i = 0; i < 2; ++i)
#pragma unroll
        for (int reg = 0; reg < 4; ++reg) {
            float vs = 0.f;
#pragma unroll
            for (int j = 0; j < 4; ++j) {
                float d = x[i][j][reg] - mean[i][reg];
                vs += d * d;
            }
            vs += __shfl_xor(vs, 1); vs += __shfl_xor(vs, 2);
            vs += __shfl_xor(vs, 4); vs += __shfl_xor(vs, 8);
            if (lrow == 0) redV[wave][i * 16 + kq * 4 + reg] = vs;
        }
    __syncthreads();

#pragma unroll
    for (int i = 0; i < 2; ++i)
#pragma unroll
        for (int reg = 0; reg < 4; ++reg) {
            const int rowp = i * 16 + kq * 4 + reg;
            if (rowp >= 25) continue;
            const float rstd = rsqrtf(
                (redV[0][rowp] + redV[1][rowp] + redV[2][rowp] + redV[3][rowp]) * (1.f / 256.f) + 1e-5f);
            const size_t ro = ((size_t)bb * 25 + rowp) * 100 + qq;
#pragma unroll
            for (int j = 0; j < 4; ++j) {
                const int col = wave * 64 + j * 16 + lrow;
                const float y = (x[i][j][reg] - mean[i][reg]) * rstd * g[col] + beta[col];
                outf[ro * 256 + col] = y;
                outbf[ro * 256 + col] = (u16)f2bf(y);
            }
        }
}

// ---------------------------------------------------------------------------
// MSDeform sampling, bf16 value, 8 channels/thread, bf16 output.
// pt-loop unrolled x2 for MLP (latency-bound L3 gathers).
// ---------------------------------------------------------------------------
__global__ __launch_bounds__(256, 4) void msdeform_sample_kernel(
    const u16* __restrict__ value,
    const float* __restrict__ off,
    const float* __restrict__ awl,
    const float* __restrict__ refp,
    u16* __restrict__ sampled)
{
    const int unit = blockIdx.x * 8 + (threadIdx.x >> 5);
    const int t = threadIdx.x & 31;
    const int h = t >> 2, c8 = t & 3;
    const int b = unit / LQ, lq = unit - b * LQ;
    const int q = lq / NPTS;

    const float* awp = awl + (size_t)unit * 128 + h * 16;
    float w[16];
    float mx = -1e30f;
#pragma unroll
    for (int k = 0; k < 16; ++k) { w[k] = awp[k]; mx = fmaxf(mx, w[k]); }
    float sum = 0.f;
#pragma unroll
    for (int k = 0; k < 16; ++k) { w[k] = __expf(w[k] - mx); sum += w[k]; }
    const float inv = 1.f / sum;

    const float* offp = off + (size_t)unit * 256 + h * 32;
    const float* rp = refp + ((size_t)b * 100 + q) * 8;
    const u16* vbase = value + (size_t)b * LEN_IN * 256 + h * 32 + c8 * 8;

    float acc[8];
#pragma unroll
    for (int k = 0; k < 8; ++k) acc[k] = 0.f;

    int start = 0;
    const int sz[4] = {128, 64, 32, 16};
#pragma unroll
    for (int l = 0; l < 4; ++l) {
        const int hh = sz[l], ww = sz[l];
        const float rx = rp[l * 2 + 0], ry = rp[l * 2 + 1];
#pragma unroll 2
        for (int pt = 0; pt < 4; ++pt) {
            float ox = offp[(l * 4 + pt) * 2 + 0];
            float oy = offp[(l * 4 + pt) * 2 + 1];
            float x = rx * ww + ox - 0.5f;
            float y = ry * hh + oy - 0.5f;
            float x0f = floorf(x), y0f = floorf(y);
            float wx = x - x0f, wy = y - y0f;
            int x0 = (int)x0f, y0 = (int)y0f;
            int x1 = x0 + 1, y1 = y0 + 1;
            float aw = w[l * 4 + pt] * inv;

            int x0c = min(max(x0, 0), ww - 1), x1c = min(max(x1, 0), ww - 1);
            int y0c = min(max(y0, 0), hh - 1), y1c = min(max(y1, 0), hh - 1);
            float w00 = aw * (1.f - wx) * (1.f - wy);
            float w10 = aw * wx * (1.f - wy);
            float w01 = aw * (1.f - wx) * wy;
            float w11 = aw * wx * wy;
            if (!(x0 >= 0 && x0 < ww)) { w00 = 0.f; w01 = 0.f; }
            if (!(x1 >= 0 && x1 < ww)) { w10 = 0.f; w11 = 0.f; }
            if (!(y0 >= 0 && y0 < hh)) { w00 = 0.f; w10 = 0.f; }
            if (!(y1 >= 0 && y1 < hh)) { w01 = 0.f; w11 = 0.f; }

            uint4 u00 = *(const uint4*)(vbase + (size_t)(start + y0c * ww + x0c) * 256);
            uint4 u10 = *(const uint4*)(vbase + (size_t)(start + y0c * ww + x1c) * 256);
            uint4 u01 = *(const uint4*)(vbase + (size_t)(start + y1c * ww + x0c) * 256);
            uint4 u11 = *(const uint4*)(vbase + (size_t)(start + y1c * ww + x1c) * 256);

#define ACC4(u, wgt) \
            acc[0] = fmaf(wgt, bf_lo(u.x), acc[0]); \
            acc[1] = fmaf(wgt, bf_hi(u.x), acc[1]); \
            acc[2] = fmaf(wgt, bf_lo(u.y), acc[2]); \
            acc[3] = fmaf(wgt, bf_hi(u.y), acc[3]); \
            acc[4] = fmaf(wgt, bf_lo(u.z), acc[4]); \
            acc[5] = fmaf(wgt, bf_hi(u.z), acc[5]); \
            acc[6] = fmaf(wgt, bf_lo(u.w), acc[6]); \
            acc[7] = fmaf(wgt, bf_hi(u.w), acc[7]);
            ACC4(u00, w00); ACC4(u10, w10); ACC4(u01, w01); ACC4(u11, w11);
#undef ACC4
        }
        start += hh * ww;
    }

    uint4 pk;
    pk.x = pack2(acc[0], acc[1]); pk.y = pack2(acc[2], acc[3]);
    pk.z = pack2(acc[4], acc[5]); pk.w = pack2(acc[6], acc[7]);
    *(uint4*)(sampled + (size_t)unit * 256 + h * 32 + c8 * 8) = pk;
}

// ---------------------------------------------------------------------------
extern "C" void kernel_launch(void* const* d_in, const int* in_sizes, int n_in,
                              void* d_out, int out_size, void* d_ws, size_t ws_size,
                              hipStream_t stream)
{
    (void)in_sizes; (void)n_in; (void)out_size; (void)ws_size;

    const float* tgt        = (const float*)d_in[0];
    const float* query_pos  = (const float*)d_in[1];
    const float* refp       = (const float*)d_in[2];
    const float* src        = (const float*)d_in[3];
    const float* w_in_intra = (const float*)d_in[4];
    const float* b_in_intra = (const float*)d_in[5];
    const float* w_out_intra= (const float*)d_in[6];
    const float* b_out_intra= (const float*)d_in[7];
    const float* g_ln_intra = (const float*)d_in[8];
    const float* b_ln_intra = (const float*)d_in[9];
    const float* w_in_inter = (const float*)d_in[10];
    const float* b_in_inter = (const float*)d_in[11];
    const float* w_out_inter= (const float*)d_in[12];
    const float* b_out_inter= (const float*)d_in[13];
    const float* g_ln_inter = (const float*)d_in[14];
    const float* b_ln_inter = (const float*)d_in[15];
    const float* off_w      = (const float*)d_in[16];
    const float* off_b      = (const float*)d_in[17];
    const float* aw_w       = (const float*)d_in[18];
    const float* aw_b       = (const float*)d_in[19];
    const float* val_w      = (const float*)d_in[20];
    const float* val_b      = (const float*)d_in[21];
    const float* co_w       = (const float*)d_in[22];
    const float* co_b       = (const float*)d_in[23];
    const float* g_ln_cross = (const float*)d_in[24];
    const float* b_ln_cross = (const float*)d_in[25];
    const float* lin1_w     = (const float*)d_in[26];
    const float* lin1_b     = (const float*)d_in[27];
    const float* lin2_w     = (const float*)d_in[28];
    const float* lin2_b     = (const float*)d_in[29];
    const float* g_ln3      = (const float*)d_in[30];
    const float* b_ln3      = (const float*)d_in[31];

    // Workspace layout (float units). Total ~37.4M floats = 150 MB.
    float* ws    = (float*)d_ws;
    float* qkv   = ws;                     // 7,680,000 fp32 (u16 qkvb overlay)
    float* tmp   = ws + 7680000;           // 2,560,000 fp32 (unused now)
    u16*   attnb = (u16*)(ws + 10240000);  // 2,560,000 u16
    float* tgt1  = ws + 11520000;          // 2,560,000 fp32 (offsets)
    float* ti    = ws + 14080000;          // 2,560,000 fp32
    u16*   tib   = (u16*)(ws + 16640000);  // 2,560,000 u16
    float* tA    = ws + 17920000;          // 2,560,000 fp32
    u16*   qcb   = (u16*)(ws + 20480000);  // 2,560,000 u16
    u16*   x1b   = (u16*)(ws + 21760000);  // 2,560,000 u16
    u16*   tgtb  = (u16*)(ws + 23040000);  // 2,560,000 u16
    float* awl   = ws + 24320000;          // 1,280,000 fp32
    u16*   valueb= (u16*)(ws + 25600000);  // 22,282,240 u16 (hidden overlays)
    u16*   wb    = (u16*)(ws + 36741120);  // 1,277,952 u16
    float* out   = (float*)d_out;
    (void)tmp;

    u16* qkvb = (u16*)qkv;                 // bf16 qkv (intra + inter paths)

    // bf16 weight segment offsets in wb
    u16* wb_in_intra  = wb;
    u16* wb_out_intra = wb + 196608;
    u16* wb_in_inter  = wb + 262144;
    u16* wb_out_inter = wb + 458752;
    u16* wb_off       = wb + 524288;   // rows 0..255: off_w; 256..383: aw_w
    u16* wb_co        = wb + 688128;
    u16* wb_lin1      = wb + 753664;
    u16* wb_lin2      = wb + 1015808;

    const float scale = 0.17677669529663687f;  // 1/sqrt(32)
    const int MB64  = (M10K + 63) / 64;        // 157
    const int MB128 = (M10K + 127) / 128;      // 79

    // ---- stage 0: weight conversion + (tgt+qpos) convert + VALUE GEMM ----
    fat_stage0_kernel<<<4594, 256, 0, stream>>>(
        w_in_intra, w_out_intra, w_in_inter, w_out_inter, off_w,
        aw_w, val_w, co_w, lin1_w, lin2_w, wb,
        tgt, query_pos, x1b, tgtb,
        src, val_w, val_b, valueb);

    // ---- stage 1: intra QK GEMM + intra V GEMM ----
    fat_stage1_kernel<<<944, 256, 0, stream>>>(
        x1b, wb_in_intra, b_in_intra, qkvb,
        tgtb, wb_in_intra + 512 * 256, b_in_intra + 512, qkvb + 512);

    // ---- intra self-attention + out-proj + LN (fused, one launch) ----
    intra_fused_kernel<<<400, 256, 0, stream>>>(qkvb, wb_out_intra, b_out_intra,
                                                tgt, g_ln_intra, b_ln_intra,
                                                ti, tib, scale);

    // ---- inter-instance self-attention (over 100 queries) ----
    gemm_mfma128_kernel<<<dim3(6, MB128), 256, 0, stream>>>(tib, 256, wb_in_inter, 256,
                                                            b_in_inter, qkvb, 768, M10K, 0, 1);
    inter_attn_mfma_kernel<<<dim3(100, 8), 256, 0, stream>>>(qkvb, attnb, scale);
    // fused out-proj + residual(ti) + LN + transpose-to-tgt + qc = bf16(ln+qpos)
    gemm_ln64_kernel<<<MB64, 256, 0, stream>>>(attnb, 256, wb_out_inter, 256,
                                               b_out_inter, ti, g_ln_inter, b_ln_inter,
                                               tA, (u16*)0, query_pos, qcb, 1);

    // ---- deformable cross-attention ----
    // offsets (cols 0..255 -> tgt1) + aw logits (256..383 -> awl), one GEMM
    gemm_mfma_kernel<<<dim3(6, MB64), 256, 0, stream>>>(qcb, 256, wb_off, 256,
                                                        off_b, tgt1, 256, M10K, 0, 0,
                                                        256, aw_b, awl, 128);
    msdeform_sample_kernel<<<1250, 256, 0, stream>>>(valueb, tgt1, awl, refp, attnb);
    // fused co-proj + residual(tA) + LN -> tgt2 (ti fp32 + tib bf16)
    gemm_ln64_kernel<<<MB64, 256, 0, stream>>>(attnb, 256, wb_co, 256,
                                               co_b, tA, g_ln_cross, b_ln_cross,
                                               ti, tib, (const float*)0, (u16*)0, 0);

    // ---- FFN ----
    gemm_mfma128_kernel<<<dim3(8, MB128), 256, 0, stream>>>(tib, 256, wb_lin1, 256,
                                                            lin1_b, valueb, 1024, M10K, 1, 1);
    // fused FFN2 + residual(ti) + LN -> final output
    gemm_ln64_kernel<<<MB64, 256, 0, stream>>>(valueb, 1024, wb_lin2, 1024,
                                               lin2_b, ti, g_ln3, b_ln3,
                                               out, (u16*)0, (const float*)0, (u16*)0, 0);
}

// Round 11
// 453.458 us; speedup vs baseline: 1.0967x; 1.0967x over previous
//
#include <hip/hip_runtime.h>
#include <math.h>

// Problem constants
#define DMODEL 256
#define HEADS  8
#define HDIM   32
#define BS     4
#define NQ     100
#define NPTS   25
#define LQ     2500      // NQ*NPTS
#define M10K   10000     // BS*LQ
#define LEN_IN 21760
#define MVAL   87040     // BS*LEN_IN

typedef float f32x4 __attribute__((ext_vector_type(4)));
typedef short s16x8 __attribute__((ext_vector_type(8)));
typedef unsigned short u16;

// fp32 -> bf16 round-to-nearest-even
static __device__ __forceinline__ short f2bf(float f) {
    unsigned u = __builtin_bit_cast(unsigned, f);
    u = (u + 0x7fffu + ((u >> 16) & 1u)) >> 16;
    return (short)u;
}
static __device__ __forceinline__ unsigned pack2(float lo, float hi) {
    return (unsigned)(u16)f2bf(lo) | ((unsigned)(u16)f2bf(hi) << 16);
}
static __device__ __forceinline__ float bf_lo(unsigned u) {
    return __builtin_bit_cast(float, u << 16);
}
static __device__ __forceinline__ float bf_hi(unsigned u) {
    return __builtin_bit_cast(float, u & 0xffff0000u);
}

#define LDSK   40   // padded bf16 row stride, BK=32 tiles
#define LDSK64 72   // padded bf16 row stride, BK=64 tiles

// ---------------------------------------------------------------------------
// Value GEMM body, fp32 W converted inline (bit-identical rounding to the
// convert_weights path). C[87040,256] = bf16(A fp32) @ bf16(Wf fp32)^T + b.
// BM=64, BN=128, BK=32 (best-known R2 config — do not re-roll).
// No dependency on the weight-conversion blocks -> can co-launch with them.
// ---------------------------------------------------------------------------
static __device__ __forceinline__ void body_value64_wf32(
    char* smem_, const float* __restrict__ A, const float* __restrict__ Wf,
    const float* __restrict__ bias, u16* __restrict__ C, int bx, int by)
{
    short* As = (short*)smem_;            // 64*LDSK = 5120 B
    short* Ws = (short*)(smem_ + 5120);   // 128*LDSK = 10240 B

    const int tid = threadIdx.x;
    const int n0 = bx * 128;
    const int m0 = by * 64;

    const int arow = tid >> 2;
    const int ak = (tid & 3) * 8;
    const int wrow = tid >> 1;
    const int wk = (tid & 1) * 16;

    const float* aptr = A + (size_t)(m0 + arow) * 256 + ak;
    const float* wptr = Wf + (size_t)(n0 + wrow) * 256 + wk;

    const int wave = tid >> 6;
    const int wm = wave & 1, wn = wave >> 1;
    const int lane = tid & 63;
    const int lrow = lane & 15, kq = lane >> 4;

    f32x4 acc[2][4];
#pragma unroll
    for (int i = 0; i < 2; ++i)
#pragma unroll
        for (int j = 0; j < 4; ++j) acc[i][j] = (f32x4)(0.f);

    float4 pa0 = *(const float4*)aptr;
    float4 pa1 = *(const float4*)(aptr + 4);
    float4 pw0 = *(const float4*)(wptr);
    float4 pw1 = *(const float4*)(wptr + 4);
    float4 pw2 = *(const float4*)(wptr + 8);
    float4 pw3 = *(const float4*)(wptr + 12);

    for (int k0 = 0; k0 < 256; k0 += 32) {
        s16x8 av, wv0, wv1;
        av[0]=f2bf(pa0.x); av[1]=f2bf(pa0.y); av[2]=f2bf(pa0.z); av[3]=f2bf(pa0.w);
        av[4]=f2bf(pa1.x); av[5]=f2bf(pa1.y); av[6]=f2bf(pa1.z); av[7]=f2bf(pa1.w);
        wv0[0]=f2bf(pw0.x); wv0[1]=f2bf(pw0.y); wv0[2]=f2bf(pw0.z); wv0[3]=f2bf(pw0.w);
        wv0[4]=f2bf(pw1.x); wv0[5]=f2bf(pw1.y); wv0[6]=f2bf(pw1.z); wv0[7]=f2bf(pw1.w);
        wv1[0]=f2bf(pw2.x); wv1[1]=f2bf(pw2.y); wv1[2]=f2bf(pw2.z); wv1[3]=f2bf(pw2.w);
        wv1[4]=f2bf(pw3.x); wv1[5]=f2bf(pw3.y); wv1[6]=f2bf(pw3.z); wv1[7]=f2bf(pw3.w);
        *(s16x8*)&As[arow * LDSK + ak]     = av;
        *(s16x8*)&Ws[wrow * LDSK + wk]     = wv0;
        *(s16x8*)&Ws[wrow * LDSK + wk + 8] = wv1;
        __syncthreads();
        if (k0 + 32 < 256) {
            pa0 = *(const float4*)(aptr + k0 + 32);
            pa1 = *(const float4*)(aptr + k0 + 36);
            pw0 = *(const float4*)(wptr + k0 + 32);
            pw1 = *(const float4*)(wptr + k0 + 36);
            pw2 = *(const float4*)(wptr + k0 + 40);
            pw3 = *(const float4*)(wptr + k0 + 44);
        }

        s16x8 af[2], bfv[4];
#pragma unroll
        for (int i = 0; i < 2; ++i)
            af[i] = *(const s16x8*)&As[(wm * 32 + i * 16 + lrow) * LDSK + kq * 8];
#pragma unroll
        for (int j = 0; j < 4; ++j)
            bfv[j] = *(const s16x8*)&Ws[(wn * 64 + j * 16 + lrow) * LDSK + kq * 8];
#pragma unroll
        for (int i = 0; i < 2; ++i)
#pragma unroll
            for (int j = 0; j < 4; ++j)
                acc[i][j] = __builtin_amdgcn_mfma_f32_16x16x32_bf16(af[i], bfv[j], acc[i][j], 0, 0, 0);
        __syncthreads();
    }

#pragma unroll
    for (int i = 0; i < 2; ++i)
#pragma unroll
        for (int j = 0; j < 4; ++j) {
            int col = n0 + wn * 64 + j * 16 + lrow;
            float bv = bias[col];
#pragma unroll
            for (int reg = 0; reg < 4; ++reg) {
                int gmo = m0 + wm * 32 + i * 16 + kq * 4 + reg;
                C[(size_t)gmo * 256 + col] = (u16)f2bf(acc[i][j][reg] + bv);
            }
        }
}

// ---------------------------------------------------------------------------
// Fat stage 0: weight conversion (blocks 0..623) + add_convert (624..1873)
// + VALUE GEMM (1874..4593, fp32 W inline-converted, no dependency on the
// conversion blocks). The ~15 us of conversion work hides under the ~63 us
// value GEMM instead of serializing ahead of it.
// ---------------------------------------------------------------------------
__global__ __launch_bounds__(256) void fat_stage0_kernel(
    const float* __restrict__ s0, const float* __restrict__ s1,
    const float* __restrict__ s2, const float* __restrict__ s3,
    const float* __restrict__ s4, const float* __restrict__ s5,
    const float* __restrict__ s6, const float* __restrict__ s7,
    const float* __restrict__ s8, const float* __restrict__ s9,
    u16* __restrict__ dst,
    const float* __restrict__ a, const float* __restrict__ b,
    u16* __restrict__ xb, u16* __restrict__ ab,
    const float* __restrict__ src, const float* __restrict__ valwf,
    const float* __restrict__ valb, u16* __restrict__ valueb)
{
    __shared__ __align__(16) char smem0[15360];
    if (blockIdx.x < 624) {
        int t8 = (blockIdx.x * 256 + threadIdx.x) * 8;
        if (t8 >= 1277952) return;
        const float* s; int base;
        if      (t8 <  196608) { s = s0; base = 0;       }
        else if (t8 <  262144) { s = s1; base = 196608;  }
        else if (t8 <  458752) { s = s2; base = 262144;  }
        else if (t8 <  524288) { s = s3; base = 458752;  }
        else if (t8 <  589824) { s = s4; base = 524288;  }
        else if (t8 <  622592) { s = s5; base = 589824;  }
        else if (t8 <  688128) { s = s6; base = 622592;  }
        else if (t8 <  753664) { s = s7; base = 688128;  }
        else if (t8 < 1015808) { s = s8; base = 753664;  }
        else                   { s = s9; base = 1015808; }
        const float* p = s + (t8 - base);
        float4 fa = *(const float4*)p;
        float4 fb = *(const float4*)(p + 4);
        s16x8 v;
        v[0]=f2bf(fa.x); v[1]=f2bf(fa.y); v[2]=f2bf(fa.z); v[3]=f2bf(fa.w);
        v[4]=f2bf(fb.x); v[5]=f2bf(fb.y); v[6]=f2bf(fb.z); v[7]=f2bf(fb.w);
        *(s16x8*)(dst + t8) = v;
    } else if (blockIdx.x < 1874) {
        int i = (blockIdx.x - 624) * 256 + threadIdx.x;   // < 320000 exactly
        size_t o = (size_t)i * 8;
        float4 a0 = *(const float4*)(a + o);
        float4 a1 = *(const float4*)(a + o + 4);
        s16x8 v;
        v[0]=f2bf(a0.x); v[1]=f2bf(a0.y); v[2]=f2bf(a0.z); v[3]=f2bf(a0.w);
        v[4]=f2bf(a1.x); v[5]=f2bf(a1.y); v[6]=f2bf(a1.z); v[7]=f2bf(a1.w);
        *(s16x8*)(ab + o) = v;
        float4 b0 = *(const float4*)(b + o);
        float4 b1 = *(const float4*)(b + o + 4);
        a0.x += b0.x; a0.y += b0.y; a0.z += b0.z; a0.w += b0.w;
        a1.x += b1.x; a1.y += b1.y; a1.z += b1.z; a1.w += b1.w;
        s16x8 w;
        w[0]=f2bf(a0.x); w[1]=f2bf(a0.y); w[2]=f2bf(a0.z); w[3]=f2bf(a0.w);
        w[4]=f2bf(a1.x); w[5]=f2bf(a1.y); w[6]=f2bf(a1.z); w[7]=f2bf(a1.w);
        *(s16x8*)(xb + o) = w;
    } else {
        const int vb = blockIdx.x - 1874;        // 0..2719 = (2, 1360)
        body_value64_wf32(smem0, src, valwf, valb, valueb, vb & 1, vb >> 1);
    }
}

// ---------------------------------------------------------------------------
// Device bodies for fat stage 1 (shared 20480-B LDS buffer).
// ---------------------------------------------------------------------------

// 128x128-tile GEMM body: K=256, lda=256, ldc=768, bf16 out, M=10000 bound.
// (intra QK projection)
static __device__ __forceinline__ void body_mfma128(
    char* smem_, const u16* __restrict__ A, const u16* __restrict__ W,
    const float* __restrict__ bias, u16* __restrict__ Cv, int bx, int by)
{
    short* As = (short*)smem_;             // 10240 B
    short* Ws = (short*)(smem_ + 10240);   // 10240 B

    const int tid = threadIdx.x;
    const int m0 = by * 128, n0 = bx * 128;
    const int srow = tid >> 1;
    const int sk = (tid & 1) * 16;
    const int wave = tid >> 6;
    const int wm = wave & 1, wn = wave >> 1;
    const int lane = tid & 63;
    const int lrow = lane & 15, kq = lane >> 4;

    const int gm = m0 + srow;
    const u16* aptr = A + (size_t)gm * 256 + sk;
    const u16* wptr = W + (size_t)(n0 + srow) * 256 + sk;

    f32x4 acc[4][4];
#pragma unroll
    for (int i = 0; i < 4; ++i)
#pragma unroll
        for (int j = 0; j < 4; ++j) acc[i][j] = (f32x4)(0.f);

    s16x8 a0 = (s16x8)0, a1 = (s16x8)0, w0, w1;
    if (gm < M10K) { a0 = *(const s16x8*)aptr; a1 = *(const s16x8*)(aptr + 8); }
    w0 = *(const s16x8*)wptr; w1 = *(const s16x8*)(wptr + 8);

    for (int k0 = 0; k0 < 256; k0 += 32) {
        *(s16x8*)&As[srow * LDSK + sk]     = a0;
        *(s16x8*)&As[srow * LDSK + sk + 8] = a1;
        *(s16x8*)&Ws[srow * LDSK + sk]     = w0;
        *(s16x8*)&Ws[srow * LDSK + sk + 8] = w1;
        __syncthreads();
        if (k0 + 32 < 256) {
            if (gm < M10K) {
                a0 = *(const s16x8*)(aptr + k0 + 32);
                a1 = *(const s16x8*)(aptr + k0 + 40);
            }
            w0 = *(const s16x8*)(wptr + k0 + 32);
            w1 = *(const s16x8*)(wptr + k0 + 40);
        }

        s16x8 af[4], bfv[4];
#pragma unroll
        for (int i = 0; i < 4; ++i)
            af[i] = *(const s16x8*)&As[(wm * 64 + i * 16 + lrow) * LDSK + kq * 8];
#pragma unroll
        for (int j = 0; j < 4; ++j)
            bfv[j] = *(const s16x8*)&Ws[(wn * 64 + j * 16 + lrow) * LDSK + kq * 8];
#pragma unroll
        for (int i = 0; i < 4; ++i)
#pragma unroll
            for (int j = 0; j < 4; ++j)
                acc[i][j] = __builtin_amdgcn_mfma_f32_16x16x32_bf16(af[i], bfv[j], acc[i][j], 0, 0, 0);
        __syncthreads();
    }

#pragma unroll
    for (int i = 0; i < 4; ++i)
#pragma unroll
        for (int j = 0; j < 4; ++j) {
            int col = n0 + wn * 64 + j * 16 + lrow;
            float bv = bias[col];
#pragma unroll
            for (int reg = 0; reg < 4; ++reg) {
                int gmo = m0 + wm * 64 + i * 16 + kq * 4 + reg;
                if (gmo < M10K)
                    Cv[(size_t)gmo * 768 + col] = (u16)f2bf(acc[i][j][reg] + bv);
            }
        }
}

// 64x64-tile GEMM body, BK=64: K=256, lda=256, ldc=768, bf16 out, M=10000.
// (intra V projection)
static __device__ __forceinline__ void body_mfma64(
    char* smem_, const u16* __restrict__ A, const u16* __restrict__ W,
    const float* __restrict__ bias, u16* __restrict__ Cv, int bx, int by)
{
    short* As = (short*)smem_;            // 64*LDSK64*2 = 9216 B
    short* Ws = (short*)(smem_ + 9216);   // 9216 B

    const int tid = threadIdx.x;
    const int m0 = by * 64, n0 = bx * 64;
    const int srow = tid >> 2;
    const int sk = (tid & 3) * 16;
    const int wave = tid >> 6;
    const int wm = wave & 1, wn = wave >> 1;
    const int lane = tid & 63;
    const int lrow = lane & 15, kq = lane >> 4;

    const int gm = m0 + srow;
    const u16* aptr = A + (size_t)gm * 256 + sk;
    const u16* wptr = W + (size_t)(n0 + srow) * 256 + sk;

    f32x4 acc[2][2];
#pragma unroll
    for (int i = 0; i < 2; ++i)
#pragma unroll
        for (int j = 0; j < 2; ++j) acc[i][j] = (f32x4)(0.f);

    s16x8 a0 = (s16x8)0, a1 = (s16x8)0, w0, w1;
    if (gm < M10K) { a0 = *(const s16x8*)aptr; a1 = *(const s16x8*)(aptr + 8); }
    w0 = *(const s16x8*)wptr; w1 = *(const s16x8*)(wptr + 8);

    for (int k0 = 0; k0 < 256; k0 += 64) {
        *(s16x8*)&As[srow * LDSK64 + sk]     = a0;
        *(s16x8*)&As[srow * LDSK64 + sk + 8] = a1;
        *(s16x8*)&Ws[srow * LDSK64 + sk]     = w0;
        *(s16x8*)&Ws[srow * LDSK64 + sk + 8] = w1;
        __syncthreads();
        if (k0 + 64 < 256) {
            if (gm < M10K) {
                a0 = *(const s16x8*)(aptr + k0 + 64);
                a1 = *(const s16x8*)(aptr + k0 + 72);
            }
            w0 = *(const s16x8*)(wptr + k0 + 64);
            w1 = *(const s16x8*)(wptr + k0 + 72);
        }

#pragma unroll
        for (int s = 0; s < 2; ++s) {
            s16x8 af[2], bfv[2];
#pragma unroll
            for (int i = 0; i < 2; ++i)
                af[i] = *(const s16x8*)&As[(wm * 32 + i * 16 + lrow) * LDSK64 + s * 32 + kq * 8];
#pragma unroll
            for (int j = 0; j < 2; ++j)
                bfv[j] = *(const s16x8*)&Ws[(wn * 32 + j * 16 + lrow) * LDSK64 + s * 32 + kq * 8];
#pragma unroll
            for (int i = 0; i < 2; ++i)
#pragma unroll
                for (int j = 0; j < 2; ++j)
                    acc[i][j] = __builtin_amdgcn_mfma_f32_16x16x32_bf16(af[i], bfv[j], acc[i][j], 0, 0, 0);
        }
        __syncthreads();
    }

#pragma unroll
    for (int i = 0; i < 2; ++i)
#pragma unroll
        for (int j = 0; j < 2; ++j) {
            int col = n0 + wn * 32 + j * 16 + lrow;
            float bv = bias[col];
#pragma unroll
            for (int reg = 0; reg < 4; ++reg) {
                int gmo = m0 + wm * 32 + i * 16 + kq * 4 + reg;
                if (gmo < M10K)
                    Cv[(size_t)gmo * 768 + col] = (u16)f2bf(acc[i][j][reg] + bv);
            }
        }
}

// ---------------------------------------------------------------------------
// Fat stage 1: intra-QK GEMM (blocks 0..315) + intra-V GEMM (316..943).
// ---------------------------------------------------------------------------
__global__ __launch_bounds__(256) void fat_stage1_kernel(
    const u16* __restrict__ x1b, const u16* __restrict__ wqk,
    const float* __restrict__ bqk, u16* __restrict__ qkvb,
    const u16* __restrict__ tgtb, const u16* __restrict__ wv,
    const float* __restrict__ bv, u16* __restrict__ qkvb_v)
{
    __shared__ __align__(16) char smem[20480];
    const int b = blockIdx.x;
    if (b < 316) {                               // 316 = (4, 79)
        body_mfma128(smem, x1b, wqk, bqk, qkvb, b & 3, b >> 2);
    } else {
        const int bb = b - 316;                  // 628 = (4, 157)
        body_mfma64(smem, tgtb, wv, bv, qkvb_v, bb & 3, bb >> 2);
    }
}

// ---------------------------------------------------------------------------
// 64x64-tile bf16 MFMA GEMM, BK=64, register prefetch (standalone).
// C[M,N] = A[M,K] @ W[N,K]^T + bias[N]. K % 64 == 0.
// Dual-output: cols >= ncut go to Cv2 (fp32, ldc2) with bias2.
// ---------------------------------------------------------------------------
__global__ __launch_bounds__(256) void gemm_mfma_kernel(
    const u16* __restrict__ A, int lda,
    const u16* __restrict__ W, int K,
    const float* __restrict__ bias,
    void* __restrict__ Cv, int ldc,
    int M, int relu, int out_bf16,
    int ncut, const float* __restrict__ bias2,
    float* __restrict__ Cv2, int ldc2)
{
    __shared__ short As[64 * LDSK64];   // 9.2 KB
    __shared__ short Ws[64 * LDSK64];   // 9.2 KB

    const int tid = threadIdx.x;
    const int m0 = blockIdx.y * 64, n0 = blockIdx.x * 64;
    const int srow = tid >> 2;
    const int sk = (tid & 3) * 16;      // 0,16,32,48
    const int wave = tid >> 6;
    const int wm = wave & 1, wn = wave >> 1;
    const int lane = tid & 63;
    const int lrow = lane & 15;
    const int kq = lane >> 4;

    const int gm = m0 + srow;
    const u16* aptr = A + (size_t)gm * lda + sk;
    const u16* wptr = W + (size_t)(n0 + srow) * K + sk;

    f32x4 acc[2][2];
#pragma unroll
    for (int i = 0; i < 2; ++i)
#pragma unroll
        for (int j = 0; j < 2; ++j) acc[i][j] = (f32x4)(0.f);

    s16x8 a0 = (s16x8)0, a1 = (s16x8)0, w0, w1;
    if (gm < M) { a0 = *(const s16x8*)aptr; a1 = *(const s16x8*)(aptr + 8); }
    w0 = *(const s16x8*)wptr; w1 = *(const s16x8*)(wptr + 8);

    for (int k0 = 0; k0 < K; k0 += 64) {
        *(s16x8*)&As[srow * LDSK64 + sk]     = a0;
        *(s16x8*)&As[srow * LDSK64 + sk + 8] = a1;
        *(s16x8*)&Ws[srow * LDSK64 + sk]     = w0;
        *(s16x8*)&Ws[srow * LDSK64 + sk + 8] = w1;
        __syncthreads();
        if (k0 + 64 < K) {
            if (gm < M) {
                a0 = *(const s16x8*)(aptr + k0 + 64);
                a1 = *(const s16x8*)(aptr + k0 + 72);
            }
            w0 = *(const s16x8*)(wptr + k0 + 64);
            w1 = *(const s16x8*)(wptr + k0 + 72);
        }

#pragma unroll
        for (int s = 0; s < 2; ++s) {
            s16x8 af[2], bfv[2];
#pragma unroll
            for (int i = 0; i < 2; ++i)
                af[i] = *(const s16x8*)&As[(wm * 32 + i * 16 + lrow) * LDSK64 + s * 32 + kq * 8];
#pragma unroll
            for (int j = 0; j < 2; ++j)
                bfv[j] = *(const s16x8*)&Ws[(wn * 32 + j * 16 + lrow) * LDSK64 + s * 32 + kq * 8];
#pragma unroll
            for (int i = 0; i < 2; ++i)
#pragma unroll
                for (int j = 0; j < 2; ++j)
                    acc[i][j] = __builtin_amdgcn_mfma_f32_16x16x32_bf16(af[i], bfv[j], acc[i][j], 0, 0, 0);
        }
        __syncthreads();
    }

#pragma unroll
    for (int i = 0; i < 2; ++i)
#pragma unroll
        for (int j = 0; j < 2; ++j) {
            int col = n0 + wn * 32 + j * 16 + lrow;
            float bv = (col < ncut) ? bias[col] : bias2[col - ncut];
#pragma unroll
            for (int reg = 0; reg < 4; ++reg) {
                int gmo = m0 + wm * 32 + i * 16 + kq * 4 + reg;
                if (gmo < M) {
                    float v = acc[i][j][reg] + bv;
                    if (relu) v = fmaxf(v, 0.f);
                    if (col < ncut) {
                        if (out_bf16)
                            ((u16*)Cv)[(size_t)gmo * ldc + col] = (u16)f2bf(v);
                        else
                            ((float*)Cv)[(size_t)gmo * ldc + col] = v;
                    } else {
                        Cv2[(size_t)gmo * ldc2 + (col - ncut)] = v;
                    }
                }
            }
        }
}

// ---------------------------------------------------------------------------
// 128x128-tile bf16 MFMA GEMM, BK=64. K % 64 == 0. (inter QKV, FFN1)
// ---------------------------------------------------------------------------
__global__ __launch_bounds__(256) void gemm_mfma128_kernel(
    const u16* __restrict__ A, int lda,
    const u16* __restrict__ W, int K,
    const float* __restrict__ bias,
    void* __restrict__ Cv, int ldc,
    int M, int relu, int out_bf16)
{
    __shared__ short As[128 * LDSK64];   // 18.4 KB
    __shared__ short Ws[128 * LDSK64];   // 18.4 KB

    const int tid = threadIdx.x;
    const int m0 = blockIdx.y * 128, n0 = blockIdx.x * 128;

    const int srow = tid >> 1;            // 0..127
    const int sk = (tid & 1) * 32;        // 0 or 32

    const int wave = tid >> 6;
    const int wm = wave & 1, wn = wave >> 1;
    const int lane = tid & 63;
    const int lrow = lane & 15;
    const int kq = lane >> 4;

    const int gm = m0 + srow;
    const u16* aptr = A + (size_t)gm * lda + sk;
    const u16* wptr = W + (size_t)(n0 + srow) * K + sk;

    f32x4 acc[4][4];
#pragma unroll
    for (int i = 0; i < 4; ++i)
#pragma unroll
        for (int j = 0; j < 4; ++j) acc[i][j] = (f32x4)(0.f);

    s16x8 a0 = (s16x8)0, a1 = (s16x8)0, a2 = (s16x8)0, a3 = (s16x8)0;
    s16x8 w0, w1, w2, w3;
    if (gm < M) {
        a0 = *(const s16x8*)aptr;        a1 = *(const s16x8*)(aptr + 8);
        a2 = *(const s16x8*)(aptr + 16); a3 = *(const s16x8*)(aptr + 24);
    }
    w0 = *(const s16x8*)wptr;        w1 = *(const s16x8*)(wptr + 8);
    w2 = *(const s16x8*)(wptr + 16); w3 = *(const s16x8*)(wptr + 24);

    for (int k0 = 0; k0 < K; k0 += 64) {
        *(s16x8*)&As[srow * LDSK64 + sk]      = a0;
        *(s16x8*)&As[srow * LDSK64 + sk + 8]  = a1;
        *(s16x8*)&As[srow * LDSK64 + sk + 16] = a2;
        *(s16x8*)&As[srow * LDSK64 + sk + 24] = a3;
        *(s16x8*)&Ws[srow * LDSK64 + sk]      = w0;
        *(s16x8*)&Ws[srow * LDSK64 + sk + 8]  = w1;
        *(s16x8*)&Ws[srow * LDSK64 + sk + 16] = w2;
        *(s16x8*)&Ws[srow * LDSK64 + sk + 24] = w3;
        __syncthreads();
        if (k0 + 64 < K) {
            if (gm < M) {
                a0 = *(const s16x8*)(aptr + k0 + 64);
                a1 = *(const s16x8*)(aptr + k0 + 72);
                a2 = *(const s16x8*)(aptr + k0 + 80);
                a3 = *(const s16x8*)(aptr + k0 + 88);
            }
            w0 = *(const s16x8*)(wptr + k0 + 64);
            w1 = *(const s16x8*)(wptr + k0 + 72);
            w2 = *(const s16x8*)(wptr + k0 + 80);
            w3 = *(const s16x8*)(wptr + k0 + 88);
        }

#pragma unroll
        for (int s = 0; s < 2; ++s) {
            s16x8 af[4], bfv[4];
#pragma unroll
            for (int i = 0; i < 4; ++i)
                af[i] = *(const s16x8*)&As[(wm * 64 + i * 16 + lrow) * LDSK64 + s * 32 + kq * 8];
#pragma unroll
            for (int j = 0; j < 4; ++j)
                bfv[j] = *(const s16x8*)&Ws[(wn * 64 + j * 16 + lrow) * LDSK64 + s * 32 + kq * 8];
#pragma unroll
            for (int i = 0; i < 4; ++i)
#pragma unroll
                for (int j = 0; j < 4; ++j)
                    acc[i][j] = __builtin_amdgcn_mfma_f32_16x16x32_bf16(af[i], bfv[j], acc[i][j], 0, 0, 0);
        }
        __syncthreads();
    }

#pragma unroll
    for (int i = 0; i < 4; ++i)
#pragma unroll
        for (int j = 0; j < 4; ++j) {
            int col = n0 + wn * 64 + j * 16 + lrow;
            float bv = bias[col];
#pragma unroll
            for (int reg = 0; reg < 4; ++reg) {
                int gmo = m0 + wm * 64 + i * 16 + kq * 4 + reg;
                if (gmo < M) {
                    float v = acc[i][j][reg] + bv;
                    if (relu) v = fmaxf(v, 0.f);
                    if (out_bf16)
                        ((u16*)Cv)[(size_t)gmo * ldc + col] = (u16)f2bf(v);
                    else
                        ((float*)Cv)[(size_t)gmo * ldc + col] = v;
                }
            }
        }
}

// ---------------------------------------------------------------------------
// Inter attention (S=100) via MFMA flash, bf16 qkv input.
// One block (256 thr) per (b,h).
// ---------------------------------------------------------------------------
__global__ __launch_bounds__(256) void inter_attn_mfma_kernel(
    const u16* __restrict__ qkv, u16* __restrict__ out, float scale)
{
    __shared__ __align__(16) u16 Qs[112 * 40];
    __shared__ __align__(16) u16 Ks[112 * 40];
    __shared__ __align__(16) u16 Vt[32 * 136];
    __shared__ __align__(16) u16 Ps[112 * 136];

    const int b = blockIdx.x, h = blockIdx.y;
    const u16* base = qkv + (size_t)b * 100 * 768;
    const int tid = threadIdx.x;
    const int wave = tid >> 6, lane = tid & 63;
    const int lr = lane & 15, quad = lane >> 4;

    for (int i = tid; i < 12 * 20; i += 256) {
        int row = 100 + i / 20, c = (i % 20) * 2;
        *(unsigned*)&Qs[row * 40 + c] = 0;
        *(unsigned*)&Ks[row * 40 + c] = 0;
    }
    for (int i = tid; i < 2176; i += 256) ((unsigned*)Vt)[i] = 0;
    for (int i = tid; i < 7616; i += 256) ((unsigned*)Ps)[i] = 0;
    __syncthreads();

    for (int idx = tid; idx < 2400; idx += 256) {
        int row = idx / 24, s = idx % 24;
        const u16* p = (s < 8)  ? base + row * 768 + h * 32 + s * 4
                     : (s < 16) ? base + row * 768 + 256 + h * 32 + (s - 8) * 4
                                : base + row * 768 + 512 + h * 32 + (s - 16) * 4;
        if (s < 8) {
            *(uint2*)&Qs[row * 40 + s * 4] = *(const uint2*)p;
        } else if (s < 16) {
            *(uint2*)&Ks[row * 40 + (s - 8) * 4] = *(const uint2*)p;
        } else {
            int d0 = (s - 16) * 4;
            Vt[(d0 + 0) * 136 + row] = p[0];
            Vt[(d0 + 1) * 136 + row] = p[1];
            Vt[(d0 + 2) * 136 + row] = p[2];
            Vt[(d0 + 3) * 136 + row] = p[3];
        }
    }
    __syncthreads();

#pragma unroll 1
    for (int rr = 0; rr < 2; ++rr) {
        int rt = wave + rr * 4;
        if (rt < 7) {
            s16x8 aq = *(const s16x8*)&Qs[(rt * 16 + lr) * 40 + quad * 8];
            f32x4 sc[7];
#pragma unroll
            for (int ct = 0; ct < 7; ++ct) {
                s16x8 bk = *(const s16x8*)&Ks[(ct * 16 + lr) * 40 + quad * 8];
                sc[ct] = __builtin_amdgcn_mfma_f32_16x16x32_bf16(aq, bk, (f32x4)(0.f), 0, 0, 0);
            }
            const bool colok[7] = {true, true, true, true, true, true, (lr < 4)};
#pragma unroll
            for (int reg = 0; reg < 4; ++reg) {
                float mx = -1e30f;
#pragma unroll
                for (int ct = 0; ct < 7; ++ct) {
                    float sv = sc[ct][reg] * scale;
                    sc[ct][reg] = sv;
                    if (colok[ct]) mx = fmaxf(mx, sv);
                }
#pragma unroll
                for (int d = 1; d < 16; d <<= 1) mx = fmaxf(mx, __shfl_xor(mx, d));
                float ssum = 0.f;
#pragma unroll
                for (int ct = 0; ct < 7; ++ct) {
                    float pv = colok[ct] ? __expf(sc[ct][reg] - mx) : 0.f;
                    sc[ct][reg] = pv;
                    ssum += pv;
                }
#pragma unroll
                for (int d = 1; d < 16; d <<= 1) ssum += __shfl_xor(ssum, d);
                float inv = 1.f / ssum;
                int prow = rt * 16 + quad * 4 + reg;
#pragma unroll
                for (int ct = 0; ct < 7; ++ct)
                    Ps[prow * 136 + ct * 16 + lr] = (u16)f2bf(sc[ct][reg] * inv);
            }
        }
    }
    __syncthreads();

#pragma unroll 1
    for (int rr = 0; rr < 2; ++rr) {
        int rt = wave + rr * 4;
        if (rt < 7) {
            f32x4 o0 = (f32x4)(0.f), o1 = (f32x4)(0.f);
#pragma unroll
            for (int kk = 0; kk < 4; ++kk) {
                s16x8 ap = *(const s16x8*)&Ps[(rt * 16 + lr) * 136 + kk * 32 + quad * 8];
                s16x8 bv0 = *(const s16x8*)&Vt[lr * 136 + kk * 32 + quad * 8];
                s16x8 bv1 = *(const s16x8*)&Vt[(16 + lr) * 136 + kk * 32 + quad * 8];
                o0 = __builtin_amdgcn_mfma_f32_16x16x32_bf16(ap, bv0, o0, 0, 0, 0);
                o1 = __builtin_amdgcn_mfma_f32_16x16x32_bf16(ap, bv1, o1, 0, 0, 0);
            }
#pragma unroll
            for (int reg = 0; reg < 4; ++reg) {
                int q = rt * 16 + quad * 4 + reg;
                if (q < 100) {
                    u16* op = out + ((size_t)b * 100 + q) * 256 + h * 32;
                    op[lr]      = (u16)f2bf(o0[reg]);
                    op[16 + lr] = (u16)f2bf(o1[reg]);
                }
            }
        }
    }
}

// ---------------------------------------------------------------------------
// FUSED intra path: flash attn (S=25, bf16 qkv) + out-projection (W from L2)
// + residual + LayerNorm + transpose-to-ti write. One block per instance.
// ---------------------------------------------------------------------------
__global__ __launch_bounds__(256) void intra_fused_kernel(
    const u16* __restrict__ qkv,        // [400*25][768] bf16
    const u16* __restrict__ W,          // out-proj [256][256] bf16
    const float* __restrict__ bias,
    const float* __restrict__ res,      // tgt fp32 [10000][256]
    const float* __restrict__ g, const float* __restrict__ beta,
    float* __restrict__ outf, u16* __restrict__ outbf,  // ti / tib (mode-2)
    float scale)
{
    __shared__ __align__(16) uint2 KVh[25][128];   // 25.6 KB (K|V bf16)
    __shared__ __align__(16) u16 Ao[32 * 264];     // 16.9 KB attn out (pad rows 0)
    __shared__ short Ws[256 * LDSK];               // 20.5 KB W K-slice
    __shared__ float redS[4][32];
    __shared__ float redV[4][32];

    const int inst = blockIdx.x;                   // 0..399 = bb*100 + qq
    const int tid = threadIdx.x;
    const int h = tid >> 5, r = tid & 31;
    const u16* base = qkv + (size_t)inst * 25 * 768;

    // zero Ao pad rows 25..31 (cols read by MFMA must be 0)
    for (int i = tid; i < 7 * 132; i += 256)
        ((unsigned*)&Ao[25 * 264])[i] = 0;
    // stage K,V bf16
    for (int idx = tid; idx < 3200; idx += 256) {
        int row = idx >> 7, c = idx & 127;
        KVh[row][c] = *(const uint2*)(base + row * 768 + 256 + c * 4);
    }

    float q[32];
    if (r < 25) {
        const u16* qp = base + r * 768 + h * 32;
#pragma unroll
        for (int c4 = 0; c4 < 8; ++c4) {
            uint2 u = *(const uint2*)(qp + c4 * 4);
            q[c4*4+0] = bf_lo(u.x); q[c4*4+1] = bf_hi(u.x);
            q[c4*4+2] = bf_lo(u.y); q[c4*4+3] = bf_hi(u.y);
        }
    }
    __syncthreads();

    if (r < 25) {
        float m = -1e30f, l = 0.f, acc[32];
#pragma unroll
        for (int c = 0; c < 32; ++c) acc[c] = 0.f;
#pragma unroll 2
        for (int j = 0; j < 25; ++j) {
            const uint2* kr = &KVh[j][h * 8];
            float dot = 0.f;
#pragma unroll
            for (int c4 = 0; c4 < 8; ++c4) {
                uint2 u = kr[c4];
                dot = fmaf(q[c4*4+0], bf_lo(u.x), dot);
                dot = fmaf(q[c4*4+1], bf_hi(u.x), dot);
                dot = fmaf(q[c4*4+2], bf_lo(u.y), dot);
                dot = fmaf(q[c4*4+3], bf_hi(u.y), dot);
            }
            dot *= scale;
            float mn = fmaxf(m, dot);
            float alpha = __expf(m - mn);
            float p = __expf(dot - mn);
            l = l * alpha + p;
            const uint2* vr = &KVh[j][64 + h * 8];
#pragma unroll
            for (int c4 = 0; c4 < 8; ++c4) {
                uint2 u = vr[c4];
                acc[c4*4+0] = acc[c4*4+0] * alpha + p * bf_lo(u.x);
                acc[c4*4+1] = acc[c4*4+1] * alpha + p * bf_hi(u.x);
                acc[c4*4+2] = acc[c4*4+2] * alpha + p * bf_lo(u.y);
                acc[c4*4+3] = acc[c4*4+3] * alpha + p * bf_hi(u.y);
            }
            m = mn;
        }
        float inv = 1.f / l;
        unsigned* op = (unsigned*)&Ao[r * 264 + h * 32];
#pragma unroll
        for (int c = 0; c < 16; ++c)
            op[c] = pack2(acc[2*c] * inv, acc[2*c+1] * inv);
    }

    // ---- projection: [25(32) x 256] @ W^T, K=256, BK=32 ----
    const int wave = tid >> 6, lane = tid & 63;
    const int lrow = lane & 15, kq = lane >> 4;

    f32x4 acc2[2][4];
#pragma unroll
    for (int i = 0; i < 2; ++i)
#pragma unroll
        for (int j = 0; j < 4; ++j) acc2[i][j] = (f32x4)(0.f);

    const u16* wptr = W + (size_t)tid * 256;   // thread -> W row (out col)
    for (int k0 = 0; k0 < 256; k0 += 32) {
        __syncthreads();   // Ws free to overwrite (and Ao ready on 1st iter)
        *(s16x8*)&Ws[tid * LDSK +  0] = *(const s16x8*)(wptr + k0);
        *(s16x8*)&Ws[tid * LDSK +  8] = *(const s16x8*)(wptr + k0 + 8);
        *(s16x8*)&Ws[tid * LDSK + 16] = *(const s16x8*)(wptr + k0 + 16);
        *(s16x8*)&Ws[tid * LDSK + 24] = *(const s16x8*)(wptr + k0 + 24);
        __syncthreads();

        s16x8 af[2], bfv[4];
#pragma unroll
        for (int i = 0; i < 2; ++i)
            af[i] = *(const s16x8*)&Ao[(i * 16 + lrow) * 264 + k0 + kq * 8];
#pragma unroll
        for (int j = 0; j < 4; ++j)
            bfv[j] = *(const s16x8*)&Ws[(wave * 64 + j * 16 + lrow) * LDSK + kq * 8];
#pragma unroll
        for (int i = 0; i < 2; ++i)
#pragma unroll
            for (int j = 0; j < 4; ++j)
                acc2[i][j] = __builtin_amdgcn_mfma_f32_16x16x32_bf16(af[i], bfv[j], acc2[i][j], 0, 0, 0);
    }

    // ---- epilogue: x = res + proj + bias; two-pass LN; transposed write ----
    const int qq = inst % 100, bb = inst / 100;
    float x[2][4][4];
#pragma unroll
    for (int i = 0; i < 2; ++i)
#pragma unroll
        for (int j = 0; j < 4; ++j) {
            const int col = wave * 64 + j * 16 + lrow;
            const float bv = bias[col];
#pragma unroll
            for (int reg = 0; reg < 4; ++reg) {
                const int rowp = i * 16 + kq * 4 + reg;
                float rv = (rowp < 25) ? res[((size_t)inst * 25 + rowp) * 256 + col] : 0.f;
                x[i][j][reg] = rv + (acc2[i][j][reg] + bv);
            }
        }

#pragma unroll
    for (int i = 0; i < 2; ++i)
#pragma unroll
        for (int reg = 0; reg < 4; ++reg) {
            float s = x[i][0][reg] + x[i][1][reg] + x[i][2][reg] + x[i][3][reg];
            s += __shfl_xor(s, 1); s += __shfl_xor(s, 2);
            s += __shfl_xor(s, 4); s += __shfl_xor(s, 8);
            if (lrow == 0) redS[wave][i * 16 + kq * 4 + reg] = s;
        }
    __syncthreads();
    float mean[2][4];
#pragma unroll
    for (int i = 0; i < 2; ++i)
#pragma unroll
        for (int reg = 0; reg < 4; ++reg) {
            const int rowp = i * 16 + kq * 4 + reg;
            mean[i][reg] = (redS[0][rowp] + redS[1][rowp] + redS[2][rowp] + redS[3][rowp]) * (1.f / 256.f);
        }
#pragma unroll
    for (int i = 0; i < 2; ++i)
#pragma unroll
        for (int reg = 0; reg < 4; ++reg) {
            float vs = 0.f;
#pragma unroll
            for (int j = 0; j < 4; ++j) {
                float d = x[i][j][reg] - mean[i][reg];
                vs += d * d;
            }
            vs += __shfl_xor(vs, 1); vs += __shfl_xor(vs, 2);
            vs += __shfl_xor(vs, 4); vs += __shfl_xor(vs, 8);
            if (lrow == 0) redV[wave][i * 16 + kq * 4 + reg] = vs;
        }
    __syncthreads();

#pragma unroll
    for (int i = 0; i < 2; ++i)
#pragma unroll
        for (int reg = 0; reg < 4; ++reg) {
            const int rowp = i * 16 + kq * 4 + reg;
            if (rowp >= 25) continue;
            const float rstd = rsqrtf(
                (redV[0][rowp] + redV[1][rowp] + redV[2][rowp] + redV[3][rowp]) * (1.f / 256.f) + 1e-5f);
            const size_t ro = ((size_t)bb * 25 + rowp) * 100 + qq;
#pragma unroll
            for (int j = 0; j < 4; ++j) {
                const int col = wave * 64 + j * 16 + lrow;
                const float y = (x[i][j][reg] - mean[i][reg]) * rstd * g[col] + beta[col];
                outf[ro * 256 + col] = y;
                outbf[ro * 256 + col] = (u16)f2bf(y);
            }
        }
}

// ---------------------------------------------------------------------------
// out[row] = LN(a[row] + b[row]) * g + beta; optional bf16 mirror out_bf;
// optional qout[ro] = bf16(y + qp[ro]) (fused query+pos convert).
// transpose_mode: 0 none; 1 ti-row -> tgt-row; 2 tgt-row -> ti-row.
// Vectorized: one wave per row, float4 per lane, 4 rows/block. Grid 2500.
// ---------------------------------------------------------------------------
__global__ __launch_bounds__(256) void add_ln_kernel(
    const float* __restrict__ a, const float* __restrict__ b,
    const float* __restrict__ g, const float* __restrict__ beta,
    float* __restrict__ out, u16* __restrict__ out_bf,
    const float* __restrict__ qp, u16* __restrict__ qout,
    int transpose_mode)
{
    const int r = blockIdx.x * 4 + (threadIdx.x >> 6);
    const int lane = threadIdx.x & 63;
    const size_t co = (size_t)r * 256 + lane * 4;

    const float4 av = *(const float4*)(a + co);
    const float4 bv = *(const float4*)(b + co);
    float4 x;
    x.x = av.x + bv.x; x.y = av.y + bv.y; x.z = av.z + bv.z; x.w = av.w + bv.w;

    float s = x.x + x.y + x.z + x.w;
#pragma unroll
    for (int off = 32; off >= 1; off >>= 1) s += __shfl_xor(s, off);
    float mean = s * (1.f / 256.f);

    float dx = x.x - mean, dy = x.y - mean, dz = x.z - mean, dw = x.w - mean;
    float vs = dx * dx + dy * dy + dz * dz + dw * dw;
#pragma unroll
    for (int off = 32; off >= 1; off >>= 1) vs += __shfl_xor(vs, off);
    float rstd = rsqrtf(vs * (1.f / 256.f) + 1e-5f);

    size_t ro = r;
    if (transpose_mode == 1) {
        int q = r % 100; int bp = r / 100; int p = bp % 25; int bb = bp / 25;
        ro = ((size_t)bb * 100 + q) * 25 + p;
    } else if (transpose_mode == 2) {
        int p = r % 25; int t = r / 25; int q = t % 100; int bb = t / 100;
        ro = ((size_t)bb * 25 + p) * 100 + q;
    }
    const size_t oo = ro * 256 + lane * 4;

    const float4 gv = *(const float4*)(g + lane * 4);
    const float4 bt = *(const float4*)(beta + lane * 4);
    float4 y;
    y.x = dx * rstd * gv.x + bt.x;
    y.y = dy * rstd * gv.y + bt.y;
    y.z = dz * rstd * gv.z + bt.z;
    y.w = dw * rstd * gv.w + bt.w;

    *(float4*)(out + oo) = y;
    if (out_bf) {
        uint2 pk = make_uint2(pack2(y.x, y.y), pack2(y.z, y.w));
        *(uint2*)(out_bf + oo) = pk;
    }
    if (qout) {
        const float4 qv = *(const float4*)(qp + oo);
        uint2 pk = make_uint2(pack2(y.x + qv.x, y.y + qv.y),
                              pack2(y.z + qv.z, y.w + qv.w));
        *(uint2*)(qout + oo) = pk;
    }
}

// ---------------------------------------------------------------------------
// MSDeform sampling, bf16 value, 8 channels/thread, bf16 output.
// pt-loop unrolled x2 for MLP (latency-bound L3 gathers).
// ---------------------------------------------------------------------------
__global__ __launch_bounds__(256, 4) void msdeform_sample_kernel(
    const u16* __restrict__ value,
    const float* __restrict__ off,
    const float* __restrict__ awl,
    const float* __restrict__ refp,
    u16* __restrict__ sampled)
{
    const int unit = blockIdx.x * 8 + (threadIdx.x >> 5);
    const int t = threadIdx.x & 31;
    const int h = t >> 2, c8 = t & 3;
    const int b = unit / LQ, lq = unit - b * LQ;
    const int q = lq / NPTS;

    const float* awp = awl + (size_t)unit * 128 + h * 16;
    float w[16];
    float mx = -1e30f;
#pragma unroll
    for (int k = 0; k < 16; ++k) { w[k] = awp[k]; mx = fmaxf(mx, w[k]); }
    float sum = 0.f;
#pragma unroll
    for (int k = 0; k < 16; ++k) { w[k] = __expf(w[k] - mx); sum += w[k]; }
    const float inv = 1.f / sum;

    const float* offp = off + (size_t)unit * 256 + h * 32;
    const float* rp = refp + ((size_t)b * 100 + q) * 8;
    const u16* vbase = value + (size_t)b * LEN_IN * 256 + h * 32 + c8 * 8;

    float acc[8];
#pragma unroll
    for (int k = 0; k < 8; ++k) acc[k] = 0.f;

    int start = 0;
    const int sz[4] = {128, 64, 32, 16};
#pragma unroll
    for (int l = 0; l < 4; ++l) {
        const int hh = sz[l], ww = sz[l];
        const float rx = rp[l * 2 + 0], ry = rp[l * 2 + 1];
#pragma unroll 2
        for (int pt = 0; pt < 4; ++pt) {
            float ox = offp[(l * 4 + pt) * 2 + 0];
            float oy = offp[(l * 4 + pt) * 2 + 1];
            float x = rx * ww + ox - 0.5f;
            float y = ry * hh + oy - 0.5f;
            float x0f = floorf(x), y0f = floorf(y);
            float wx = x - x0f, wy = y - y0f;
            int x0 = (int)x0f, y0 = (int)y0f;
            int x1 = x0 + 1, y1 = y0 + 1;
            float aw = w[l * 4 + pt] * inv;

            int x0c = min(max(x0, 0), ww - 1), x1c = min(max(x1, 0), ww - 1);
            int y0c = min(max(y0, 0), hh - 1), y1c = min(max(y1, 0), hh - 1);
            float w00 = aw * (1.f - wx) * (1.f - wy);
            float w10 = aw * wx * (1.f - wy);
            float w01 = aw * (1.f - wx) * wy;
            float w11 = aw * wx * wy;
            if (!(x0 >= 0 && x0 < ww)) { w00 = 0.f; w01 = 0.f; }
            if (!(x1 >= 0 && x1 < ww)) { w10 = 0.f; w11 = 0.f; }
            if (!(y0 >= 0 && y0 < hh)) { w00 = 0.f; w10 = 0.f; }
            if (!(y1 >= 0 && y1 < hh)) { w01 = 0.f; w11 = 0.f; }

            uint4 u00 = *(const uint4*)(vbase + (size_t)(start + y0c * ww + x0c) * 256);
            uint4 u10 = *(const uint4*)(vbase + (size_t)(start + y0c * ww + x1c) * 256);
            uint4 u01 = *(const uint4*)(vbase + (size_t)(start + y1c * ww + x0c) * 256);
            uint4 u11 = *(const uint4*)(vbase + (size_t)(start + y1c * ww + x1c) * 256);

#define ACC4(u, wgt) \
            acc[0] = fmaf(wgt, bf_lo(u.x), acc[0]); \
            acc[1] = fmaf(wgt, bf_hi(u.x), acc[1]); \
            acc[2] = fmaf(wgt, bf_lo(u.y), acc[2]); \
            acc[3] = fmaf(wgt, bf_hi(u.y), acc[3]); \
            acc[4] = fmaf(wgt, bf_lo(u.z), acc[4]); \
            acc[5] = fmaf(wgt, bf_hi(u.z), acc[5]); \
            acc[6] = fmaf(wgt, bf_lo(u.w), acc[6]); \
            acc[7] = fmaf(wgt, bf_hi(u.w), acc[7]);
            ACC4(u00, w00); ACC4(u10, w10); ACC4(u01, w01); ACC4(u11, w11);
#undef ACC4
        }
        start += hh * ww;
    }

    uint4 pk;
    pk.x = pack2(acc[0], acc[1]); pk.y = pack2(acc[2], acc[3]);
    pk.z = pack2(acc[4], acc[5]); pk.w = pack2(acc[6], acc[7]);
    *(uint4*)(sampled + (size_t)unit * 256 + h * 32 + c8 * 8) = pk;
}

// ---------------------------------------------------------------------------
extern "C" void kernel_launch(void* const* d_in, const int* in_sizes, int n_in,
                              void* d_out, int out_size, void* d_ws, size_t ws_size,
                              hipStream_t stream)
{
    (void)in_sizes; (void)n_in; (void)out_size; (void)ws_size;

    const float* tgt        = (const float*)d_in[0];
    const float* query_pos  = (const float*)d_in[1];
    const float* refp       = (const float*)d_in[2];
    const float* src        = (const float*)d_in[3];
    const float* w_in_intra = (const float*)d_in[4];
    const float* b_in_intra = (const float*)d_in[5];
    const float* w_out_intra= (const float*)d_in[6];
    const float* b_out_intra= (const float*)d_in[7];
    const float* g_ln_intra = (const float*)d_in[8];
    const float* b_ln_intra = (const float*)d_in[9];
    const float* w_in_inter = (const float*)d_in[10];
    const float* b_in_inter = (const float*)d_in[11];
    const float* w_out_inter= (const float*)d_in[12];
    const float* b_out_inter= (const float*)d_in[13];
    const float* g_ln_inter = (const float*)d_in[14];
    const float* b_ln_inter = (const float*)d_in[15];
    const float* off_w      = (const float*)d_in[16];
    const float* off_b      = (const float*)d_in[17];
    const float* aw_w       = (const float*)d_in[18];
    const float* aw_b       = (const float*)d_in[19];
    const float* val_w      = (const float*)d_in[20];
    const float* val_b      = (const float*)d_in[21];
    const float* co_w       = (const float*)d_in[22];
    const float* co_b       = (const float*)d_in[23];
    const float* g_ln_cross = (const float*)d_in[24];
    const float* b_ln_cross = (const float*)d_in[25];
    const float* lin1_w     = (const float*)d_in[26];
    const float* lin1_b     = (const float*)d_in[27];
    const float* lin2_w     = (const float*)d_in[28];
    const float* lin2_b     = (const float*)d_in[29];
    const float* g_ln3      = (const float*)d_in[30];
    const float* b_ln3      = (const float*)d_in[31];

    // Workspace layout (float units). Total ~37.4M floats = 150 MB.
    float* ws    = (float*)d_ws;
    float* qkv   = ws;                     // 7,680,000 fp32 (u16 qkvb overlay)
    float* tmp   = ws + 7680000;           // 2,560,000 fp32
    u16*   attnb = (u16*)(ws + 10240000);  // 2,560,000 u16
    float* tgt1  = ws + 11520000;          // 2,560,000 fp32 (offsets)
    float* ti    = ws + 14080000;          // 2,560,000 fp32
    u16*   tib   = (u16*)(ws + 16640000);  // 2,560,000 u16
    float* tA    = ws + 17920000;          // 2,560,000 fp32
    u16*   qcb   = (u16*)(ws + 20480000);  // 2,560,000 u16
    u16*   x1b   = (u16*)(ws + 21760000);  // 2,560,000 u16
    u16*   tgtb  = (u16*)(ws + 23040000);  // 2,560,000 u16
    float* awl   = ws + 24320000;          // 1,280,000 fp32
    u16*   valueb= (u16*)(ws + 25600000);  // 22,282,240 u16 (hidden overlays)
    u16*   wb    = (u16*)(ws + 36741120);  // 1,277,952 u16
    float* out   = (float*)d_out;

    u16* qkvb = (u16*)qkv;                 // bf16 qkv (intra + inter paths)

    // bf16 weight segment offsets in wb
    u16* wb_in_intra  = wb;
    u16* wb_out_intra = wb + 196608;
    u16* wb_in_inter  = wb + 262144;
    u16* wb_out_inter = wb + 458752;
    u16* wb_off       = wb + 524288;   // rows 0..255: off_w; 256..383: aw_w
    u16* wb_co        = wb + 688128;
    u16* wb_lin1      = wb + 753664;
    u16* wb_lin2      = wb + 1015808;

    const float scale = 0.17677669529663687f;  // 1/sqrt(32)
    const int MB64  = (M10K + 63) / 64;        // 157
    const int MB128 = (M10K + 127) / 128;      // 79
    const int NC_OFF = 1 << 30;

    // ---- stage 0: weight conversion + (tgt+qpos) convert + VALUE GEMM ----
    fat_stage0_kernel<<<4594, 256, 0, stream>>>(
        w_in_intra, w_out_intra, w_in_inter, w_out_inter, off_w,
        aw_w, val_w, co_w, lin1_w, lin2_w, wb,
        tgt, query_pos, x1b, tgtb,
        src, val_w, val_b, valueb);

    // ---- stage 1: intra QK GEMM + intra V GEMM ----
    fat_stage1_kernel<<<944, 256, 0, stream>>>(
        x1b, wb_in_intra, b_in_intra, qkvb,
        tgtb, wb_in_intra + 512 * 256, b_in_intra + 512, qkvb + 512);

    // ---- intra self-attention + out-proj + LN (fused, one launch) ----
    intra_fused_kernel<<<400, 256, 0, stream>>>(qkvb, wb_out_intra, b_out_intra,
                                                tgt, g_ln_intra, b_ln_intra,
                                                ti, tib, scale);

    // ---- inter-instance self-attention (over 100 queries) ----
    gemm_mfma128_kernel<<<dim3(6, MB128), 256, 0, stream>>>(tib, 256, wb_in_inter, 256,
                                                            b_in_inter, qkvb, 768, M10K, 0, 1);
    inter_attn_mfma_kernel<<<dim3(100, 8), 256, 0, stream>>>(qkvb, attnb, scale);
    gemm_mfma_kernel<<<dim3(4, MB64), 256, 0, stream>>>(attnb, 256, wb_out_inter, 256,
                                                        b_out_inter, tmp, 256, M10K, 0, 0,
                                                        NC_OFF, b_out_inter, (float*)0, 0);
    // LN + transpose-to-tgt + fused qc = bf16(ln + qpos)
    add_ln_kernel<<<2500, 256, 0, stream>>>(ti, tmp, g_ln_inter, b_ln_inter,
                                            tA, (u16*)0, query_pos, qcb, 1);

    // ---- deformable cross-attention ----
    // offsets (cols 0..255 -> tgt1) + aw logits (256..383 -> awl), one GEMM
    gemm_mfma_kernel<<<dim3(6, MB64), 256, 0, stream>>>(qcb, 256, wb_off, 256,
                                                        off_b, tgt1, 256, M10K, 0, 0,
                                                        256, aw_b, awl, 128);
    msdeform_sample_kernel<<<1250, 256, 0, stream>>>(valueb, tgt1, awl, refp, attnb);
    gemm_mfma_kernel<<<dim3(4, MB64), 256, 0, stream>>>(attnb, 256, wb_co, 256,
                                                        co_b, tmp, 256, M10K, 0, 0,
                                                        NC_OFF, co_b, (float*)0, 0);
    add_ln_kernel<<<2500, 256, 0, stream>>>(tA, tmp, g_ln_cross, b_ln_cross,
                                            ti, tib, (const float*)0, (u16*)0, 0);  // tgt2

    // ---- FFN ----
    gemm_mfma128_kernel<<<dim3(8, MB128), 256, 0, stream>>>(tib, 256, wb_lin1, 256,
                                                            lin1_b, valueb, 1024, M10K, 1, 1);
    gemm_mfma_kernel<<<dim3(4, MB64), 256, 0, stream>>>(valueb, 1024, wb_lin2, 1024,
                                                        lin2_b, tmp, 256, M10K, 0, 0,
                                                        NC_OFF, lin2_b, (float*)0, 0);
    add_ln_kernel<<<2500, 256, 0, stream>>>(ti, tmp, g_ln3, b_ln3,
                                            out, (u16*)0, (const float*)0, (u16*)0, 0);
}